// Round 13
// baseline (791.771 us; speedup 1.0000x reference)
//
#include <hip/hip_runtime.h>
#include <hip/hip_fp16.h>

typedef _Float16 f16x8 __attribute__((ext_vector_type(8)));
typedef float f32x4 __attribute__((ext_vector_type(4)));
typedef unsigned char uchar;

static __device__ __forceinline__ long long mk64(unsigned lo, unsigned hi)
{
    return (long long)(((unsigned long long)hi << 32) | (unsigned long long)lo);
}

// fragment-layout offset for X8 (B-operand): class c, row j
static __device__ __forceinline__ int xfrag_off(int c, int j)
{
    return (j >> 6) * 1024 + (((j >> 3) & 3) * 16 + c) * 16 + ((j >> 5) & 1) * 8 + (j & 7);
}

// fragment-layout offset (halves) for Xs16f (A-operand): row (0..4095), k (0..319)
static __device__ __forceinline__ int xsfrag_off(int row, int k)
{
    return (row >> 4) * 5120 + (k >> 5) * 512 + (((k >> 3) & 3) * 16 + (row & 15)) * 8 + (k & 7);
}

// nibble codes -> fp8 e4m3 bytes of k/16 (exact): LUT via v_perm
#define T03 0x24201800u
#define T47 0x2E2C2A28u
#define T8B 0x33323130u
#define TCF 0x37363534u

static __device__ __forceinline__ void expand4(unsigned w, unsigned& o0, unsigned& o1)
{
    unsigned even = w & 0x0F0F0F0Fu;
    unsigned odd  = (w >> 4) & 0x0F0F0F0Fu;
    unsigned i_lo = __builtin_amdgcn_perm(odd, even, 0x05010400u);
    unsigned i_hi = __builtin_amdgcn_perm(odd, even, 0x07030602u);
    {
        unsigned i3 = i_lo & 0x07070707u;
        unsigned ta = __builtin_amdgcn_perm(T47, T03, i3);
        unsigned tb = __builtin_amdgcn_perm(TCF, T8B, i3);
        unsigned m  = ((i_lo >> 3) & 0x01010101u) * 0xFFu;
        o0 = ta ^ ((ta ^ tb) & m);
    }
    {
        unsigned i3 = i_hi & 0x07070707u;
        unsigned ta = __builtin_amdgcn_perm(T47, T03, i3);
        unsigned tb = __builtin_amdgcn_perm(TCF, T8B, i3);
        unsigned m  = ((i_hi >> 3) & 0x01010101u) * 0xFFu;
        o1 = ta ^ ((ta ^ tb) & m);
    }
}

// ---------------------------------------------------------------------------
// Pool for ALL levels in one dispatch. Thread = one (row, ch) instance,
// contiguous S2-float read. Block ranges: p0 [0,1024) p1 [1024,3072)
// p2 [3072,7168) p3 [7168,15360).
// ---------------------------------------------------------------------------
__global__ __launch_bounds__(256) void pool_all_kernel(
    const float* __restrict__ f0, const float* __restrict__ f1,
    const float* __restrict__ f2, const float* __restrict__ f3,
    float* __restrict__ pooled)
{
    const int b = blockIdx.x;
    const float* feat;
    int lb, pOff, S2;
    if (b < 1024)      { feat = f0; lb = b;        pOff = 0;       S2 = 64; }
    else if (b < 3072) { feat = f1; lb = b - 1024; pOff = 262144;  S2 = 64; }
    else if (b < 7168) { feat = f2; lb = b - 3072; pOff = 786432;  S2 = 16; }
    else               { feat = f3; lb = b - 7168; pOff = 1835008; S2 = 16; }
    const int idx = lb * 256 + threadIdx.x;
    const float4* src = (const float4*)(feat + (size_t)idx * S2);
    float s = 0.f;
    if (S2 == 64) {
#pragma unroll
        for (int i = 0; i < 16; ++i) { float4 v = src[i]; s += v.x + v.y + v.z + v.w; }
        pooled[pOff + idx] = s * (1.0f / 64.f);
    } else {
#pragma unroll
        for (int i = 0; i < 4; ++i) { float4 v = src[i]; s += v.x + v.y + v.z + v.w; }
        pooled[pOff + idx] = s * (1.0f / 16.f);
    }
}

// ---------------------------------------------------------------------------
// Linear+ReLU+row-normalize for all 4 levels in one dispatch.
// Grid 16384 blocks x 128 threads; p = blk>>12, row = blk&4095.
// Writes fp16 N16all[p*524288 + row*128 + t].
// ---------------------------------------------------------------------------
__global__ __launch_bounds__(128) void lsn_all_kernel(
    const float* __restrict__ pooled,
    const float* __restrict__ lw0, const float* __restrict__ lb0,
    const float* __restrict__ lw1, const float* __restrict__ lb1,
    const float* __restrict__ lw2, const float* __restrict__ lb2,
    const float* __restrict__ lw3, const float* __restrict__ lb3,
    __half* __restrict__ N16all)
{
    __shared__ float pl[512];
    __shared__ float red2[2];
    const int t = threadIdx.x;
    const int p = blockIdx.x >> 12;
    const int row = blockIdx.x & 4095;
    const float* w; const float* b; int C, pOff;
    switch (p) {
        case 0:  w = lw0; b = lb0; C = 64;  pOff = 0;       break;
        case 1:  w = lw1; b = lb1; C = 128; pOff = 262144;  break;
        case 2:  w = lw2; b = lb2; C = 256; pOff = 786432;  break;
        default: w = lw3; b = lb3; C = 512; pOff = 1835008; break;
    }
    for (int k = t; k < C; k += 128) pl[k] = pooled[pOff + (size_t)row * C + k];
    __syncthreads();
    float acc = b[t];
    for (int k = 0; k < C; ++k) acc = fmaf(pl[k], w[(size_t)k * 128 + t], acc);
    float v = fmaxf(acc, 0.f);
    float ss = v * v;
    for (int off = 32; off > 0; off >>= 1) ss += __shfl_down(ss, off, 64);
    if ((t & 63) == 0) red2[t >> 6] = ss;
    __syncthreads();
    float inv = 1.0f / fmaxf(sqrtf(red2[0] + red2[1]), 1e-12f);
    N16all[(size_t)p * 524288 + (size_t)row * 128 + t] = __float2half(v * inv);
}

// ---------------------------------------------------------------------------
// Normalize embedds rows (d=512) -> N16all + 2097152
// ---------------------------------------------------------------------------
__global__ __launch_bounds__(256) void norm512_kernel(const float* __restrict__ E,
                                                      __half* __restrict__ N16all)
{
    __shared__ float red4[4];
    const int b = blockIdx.x, t = threadIdx.x;
    float2 v = *(const float2*)(E + (size_t)b * 512 + t * 2);
    float ss = v.x * v.x + v.y * v.y;
    for (int off = 32; off > 0; off >>= 1) ss += __shfl_down(ss, off, 64);
    if ((t & 63) == 0) red4[t >> 6] = ss;
    __syncthreads();
    float inv = 1.0f / fmaxf(sqrtf(red4[0] + red4[1] + red4[2] + red4[3]), 1e-12f);
    __half2 o;
    o.x = __float2half(v.x * inv);
    o.y = __float2half(v.y * inv);
    *(__half2*)(N16all + 2097152 + (size_t)b * 512 + t * 2) = o;
}

// ---------------------------------------------------------------------------
// All-problem MFMA GEMM. Grid pcount*1024; p = pbase + blk>>10, runtime K.
// Writes fp16 C = clamp(nnT,0,1), diag=0, FRAGMENT-MAJOR, per-problem slice
// of A16f (32 MB each) + fp32 partial sums -> partials[lp*1024+blk].
// ---------------------------------------------------------------------------
__global__ __launch_bounds__(256) void a_gemm_all(const __half* __restrict__ N16all,
                                                  __half* __restrict__ A16f,
                                                  float* __restrict__ partials,
                                                  int pbase)
{
    __shared__ __half smem[16384];   // As(8192) | Bs(8192); reused as Cst
    __shared__ float reds[4];
    __half* As = smem;
    __half* Bs = smem + 8192;
    char* Cb = (char*)smem;
    const int t = threadIdx.x;
    const int lane = t & 63, wave = t >> 6;
    const int lp = blockIdx.x >> 10;
    const int p = pbase + lp;
    const int blk = blockIdx.x & 1023;
    const int K = (p == 4) ? 512 : 128;
    const __half* N16 = N16all + ((p == 4) ? 2097152u : (unsigned)p * 524288u);
    const int bx = blk & 31, by = blk >> 5;
    const int wr = wave >> 1, wc = wave & 1;
    const int fr = lane & 15;
    const int g = lane >> 4;
    const int r0 = by * 128, c0 = bx * 128;
    const int sr = t >> 3;
    const int sc = t & 7;

    f32x4 acc[4][4];
#pragma unroll
    for (int i = 0; i < 4; ++i)
#pragma unroll
        for (int j = 0; j < 4; ++j) acc[i][j] = (f32x4){0.f, 0.f, 0.f, 0.f};

    for (int kt = 0; kt < (K >> 6); ++kt) {
        const int kb = kt * 64;
        __syncthreads();
#pragma unroll
        for (int pp = 0; pp < 4; ++pp) {
            const int r = pp * 32 + sr;
            uint4 va = *(const uint4*)(N16 + (size_t)(r0 + r) * K + kb + sc * 8);
            uint4 vb = *(const uint4*)(N16 + (size_t)(c0 + r) * K + kb + sc * 8);
            const int d = r * 64 + ((((sc * 16) ^ ((r & 7) << 4))) >> 1);
            *(uint4*)&As[d] = va;
            *(uint4*)&Bs[d] = vb;
        }
        __syncthreads();
#pragma unroll
        for (int ks = 0; ks < 2; ++ks) {
            const int ko = ((ks * 64 + g * 16) ^ ((fr & 7) << 4)) >> 1;
            f16x8 af[4], bf[4];
#pragma unroll
            for (int i = 0; i < 4; ++i) {
                af[i] = *(const f16x8*)&As[(wr * 64 + i * 16 + fr) * 64 + ko];
                bf[i] = *(const f16x8*)&Bs[(wc * 64 + i * 16 + fr) * 64 + ko];
            }
#pragma unroll
            for (int i = 0; i < 4; ++i)
#pragma unroll
                for (int j = 0; j < 4; ++j)
                    acc[i][j] = __builtin_amdgcn_mfma_f32_16x16x32_f16(af[i], bf[j], acc[i][j], 0, 0, 0);
        }
    }
    __syncthreads();

    float lsum = 0.f;
    const int r4 = g * 4;
#pragma unroll
    for (int i = 0; i < 4; ++i) {
#pragma unroll
        for (int q = 0; q < 4; ++q) {
            const int lr = wr * 64 + i * 16 + r4 + q;
            const int row = r0 + lr;
#pragma unroll
            for (int j = 0; j < 4; ++j) {
                const int lc2 = wc * 64 + j * 16 + fr;
                const int col = c0 + lc2;
                float v = fminf(fmaxf(acc[i][j][q], 0.f), 1.f);
                if (row == col) v = 0.f;
                lsum += v;
                *(__half*)(Cb + lr * 256 + ((lc2 * 2) ^ ((lr & 7) << 4))) = __float2half(v);
            }
        }
    }
    __syncthreads();

#pragma unroll
    for (int pp = 0; pp < 4; ++pp) {
        const int rbl2 = pp * 4 + (t >> 6);
        const int rbl = rbl2 >> 1, ks2l = rbl2 & 1;
        const int l = t & 63;
        const int lr = rbl * 16 + (l & 15);
        const int e0 = ks2l * 64 + (l >> 4) * 8;
        uint4 v0 = *(const uint4*)(Cb + lr * 256 + ((e0 * 2) ^ ((lr & 7) << 4)));
        uint4 v1 = *(const uint4*)(Cb + lr * 256 + (((e0 + 32) * 2) ^ ((lr & 7) << 4)));
        const size_t rb = (size_t)(by * 8 + rbl);
        const size_t ks2 = (size_t)(bx * 2 + ks2l);
        char* dst = (char*)A16f + (size_t)lp * 33554432 + rb * 131072 + ks2 * 2048 + l * 32;
        *(uint4*)dst = v0;
        *(uint4*)(dst + 16) = v1;
    }

    for (int off = 32; off > 0; off >>= 1) lsum += __shfl_down(lsum, off, 64);
    if (lane == 0) reds[wave] = lsum;
    __syncthreads();
    if (t == 0) partials[lp * 1024 + blk] = reds[0] + reds[1] + reds[2] + reds[3];
}

// ---------------------------------------------------------------------------
// mean per problem: block lp reduces partials[lp][0..1023] -> scal[lp]
// ---------------------------------------------------------------------------
__global__ __launch_bounds__(256) void mean_all_kernel(const float* __restrict__ partials,
                                                       float* __restrict__ scal)
{
    __shared__ float red[4];
    const int t = threadIdx.x, lp = blockIdx.x;
    float s = 0.f;
    for (int i = t; i < 1024; i += 256) s += partials[lp * 1024 + i];
    for (int off = 32; off > 0; off >>= 1) s += __shfl_down(s, off, 64);
    if ((t & 63) == 0) red[t >> 6] = s;
    __syncthreads();
    if (t == 0) scal[lp] = (red[0] + red[1] + red[2] + red[3]) * (1.0f / 16777216.0f);
}

// ---------------------------------------------------------------------------
// Quantize to 4-bit codes round(16*(a<mean?0:a)), linear frag order.
// Grid pcount*4096; lp = blk>>12.
// ---------------------------------------------------------------------------
__global__ __launch_bounds__(256) void abar4_all_kernel(const __half* __restrict__ A16f,
                                                        uchar* __restrict__ A4,
                                                        const float* __restrict__ scal)
{
    const int lp = blockIdx.x >> 12;
    const float mean = scal[lp];
    const size_t i = (size_t)(blockIdx.x & 4095) * 256 + threadIdx.x;
    const __half* src = A16f + (size_t)lp * 16777216 + i * 16;
    uint4 u0 = *(const uint4*)(src);
    uint4 u1 = *(const uint4*)(src + 8);
    __half h[16];
    *(uint4*)h = u0;
    *(uint4*)(h + 8) = u1;
    unsigned d0 = 0, d1 = 0;
#pragma unroll
    for (int k = 0; k < 8; ++k) {
        float a = __half2float(h[k]);
        float v = (a < mean) ? 0.f : a;
        unsigned n = (unsigned)fminf(v * 16.f + 0.5f, 15.f);
        d0 |= n << (4 * k);
    }
#pragma unroll
    for (int k = 0; k < 8; ++k) {
        float a = __half2float(h[8 + k]);
        float v = (a < mean) ? 0.f : a;
        unsigned n = (unsigned)fminf(v * 16.f + 0.5f, 15.f);
        d1 |= n << (4 * k);
    }
    uint2 o; o.x = d0; o.y = d1;
    *(uint2*)(A4 + (size_t)lp * 8388608 + i * 8) = o;
}

// ---------------------------------------------------------------------------
// X0 init + Scol init (blocks 0..30) + label histogram (block 0)
// ---------------------------------------------------------------------------
__global__ __launch_bounds__(256) void init_kernel(const int* __restrict__ labels,
                                                   uchar* __restrict__ X8_0,
                                                   uchar* __restrict__ X8_1,
                                                   float* __restrict__ X32,
                                                   float* __restrict__ Scol)
{
    __shared__ int hist[16];
    const int blk = blockIdx.x;
    const int t = threadIdx.x;
    const int idx = blk * 256 + t;   // 5*16*4096 = 327680
    const int p = idx >> 16;
    const int rem = idx & 65535;
    const int c = rem >> 12, j = rem & 4095;
    float v;
    if (c >= 10) v = 0.f;
    else if (j < 2048) v = (labels[j] == c) ? 1.0f : 0.0f;
    else v = 0.1f;
    unsigned pk = __builtin_amdgcn_cvt_pk_fp8_f32(v, v, 0, false);
    X8_0[(size_t)p * 65536 + xfrag_off(c, j)] = (uchar)(pk & 0xff);
    if (c >= 10) X8_1[(size_t)p * 65536 + xfrag_off(c, j)] = 0;
    if (c < 10) X32[((size_t)p * 4096 + j) * 10 + c] = v;

    if (blk == 0) {
        if (t < 16) hist[t] = 0;
        __syncthreads();
        for (int i = t; i < 2048; i += 256) atomicAdd(&hist[labels[i]], 1);
        __syncthreads();
        if (t < 80) {
            const int pp = t >> 4, cc = t & 15;
            Scol[pp * 16 + cc] = (cc < 10) ? ((float)hist[cc] + 204.8f) : 0.f;
        }
    } else if (blk <= 30) {
        if (t < 80) Scol[blk * 80 + t] = 0.f;
    }
}

// ---------------------------------------------------------------------------
// Pack w1 (300x150) and w2 (150x75) into fragment-major fp16 B-operand form.
// ---------------------------------------------------------------------------
__global__ __launch_bounds__(256) void wfrag_kernel(const float* __restrict__ w1,
                                                    const float* __restrict__ w2,
                                                    __half* __restrict__ W1f,
                                                    __half* __restrict__ W2f)
{
    int idx = blockIdx.x * 256 + threadIdx.x;   // 51200 + 12800 = 64000
    if (idx < 51200) {
        const int frag = idx >> 9, e9 = idx & 511;
        const int s = frag / 10, j = frag % 10;
        const int g = e9 >> 7, fr = (e9 >> 3) & 15, e = e9 & 7;
        const int k = s * 32 + g * 8 + e, n = j * 16 + fr;
        const float v = (k < 300 && n < 150) ? w1[(size_t)k * 150 + n] : 0.f;
        W1f[idx] = __float2half(v);
    } else if (idx < 64000) {
        const int i2 = idx - 51200;
        const int frag = i2 >> 9, e9 = i2 & 511;
        const int s = frag / 5, j = frag % 5;
        const int g = e9 >> 7, fr = (e9 >> 3) & 15, e = e9 & 7;
        const int k = s * 32 + g * 8 + e, n = j * 16 + fr;
        const float v = (k < 150 && n < 75) ? w2[(size_t)k * 75 + n] : 0.f;
        W2f[i2] = __float2half(v);
    }
}

// ---------------------------------------------------------------------------
// One GTG iteration: 4-bit A expanded in-register to fp8 (LUT), fp8 MFMA.
// 5 blocks/CU residency (min 5 waves/EU).
// ---------------------------------------------------------------------------
__global__ __launch_bounds__(256, 5) void gtg8_kernel(
    const uchar* __restrict__ A4f,
    const uchar* __restrict__ X8i, uchar* __restrict__ X8o,
    const float* __restrict__ X32i, float* __restrict__ X32o,
    __half* __restrict__ Xs16f, float* __restrict__ ytacc,
    float* __restrict__ Scol, int it, int pbase)
{
    __shared__ float yred[4][256];
    const int t = threadIdx.x;
    const int lane = t & 63, wave = t >> 6;
    const int p = pbase + (blockIdx.x >> 8);
    const int pl = p - pbase;
    const int rb = blockIdx.x & 255;

    const uchar* Ab = A4f + (size_t)pl * 8388608 + (size_t)rb * 32768
                    + wave * 8192 + lane * 8;
    const uchar* Xb = X8i + (size_t)p * 65536 + wave * 16384 + lane * 16;

    f32x4 acc0 = {0.f, 0.f, 0.f, 0.f};
    f32x4 acc1 = {0.f, 0.f, 0.f, 0.f};
#pragma unroll
    for (int u = 0; u < 16; ++u) {
        uint2 a4 = *(const uint2*)(Ab + u * 512);
        uint4 bv = *(const uint4*)(Xb + u * 1024);
        unsigned e00, e01, e10, e11;
        expand4(a4.x, e00, e01);
        expand4(a4.y, e10, e11);
        acc0 = __builtin_amdgcn_mfma_f32_16x16x32_fp8_fp8(
            mk64(e00, e01), mk64(bv.x, bv.y), acc0, 0, 0, 0);
        acc1 = __builtin_amdgcn_mfma_f32_16x16x32_fp8_fp8(
            mk64(e10, e11), mk64(bv.z, bv.w), acc1, 0, 0, 0);
    }
    {
        const int r4 = (lane >> 4) * 4;
        const int fr = lane & 15;
#pragma unroll
        for (int q = 0; q < 4; ++q)
            yred[wave][(r4 + q) * 16 + fr] = acc0[q] + acc1[q];
    }
    __syncthreads();

    // ---- update phase: thread t -> row r=t>>4, class c=t&15
    const int r = t >> 4, c = t & 15;
    const int row = rb * 16 + r;
    const float T = yred[0][t] + yred[1][t] + yred[2][t] + yred[3][t];
    const float y = Scol[it * 80 + pl * 16 + c] - T;
    const float x = (c < 10) ? X32i[((size_t)p * 4096 + row) * 10 + c] : 0.f;
    const float m = x * y;
    float s = m;
    s += __shfl_xor(s, 1, 16);
    s += __shfl_xor(s, 2, 16);
    s += __shfl_xor(s, 4, 16);
    s += __shfl_xor(s, 8, 16);
    const float dv = m / (s + 1e-8f);
    const float xn = x + dv;
    if (c < 10) {
        X32o[((size_t)p * 4096 + row) * 10 + c] = xn;
        unsigned pk = __builtin_amdgcn_cvt_pk_fp8_f32(xn, xn, 0, false);
        X8o[(size_t)p * 65536 + xfrag_off(c, row)] = (uchar)(pk & 0xff);
        if (p < 4) {
            const int k = c * 30 + it;
            Xs16f[(size_t)p * 1310720 + xsfrag_off(row, k)] = __float2half(xn);
        }
    }
    if (p == 4) {
        float e = (c < 10) ? (-dv * logf(dv + 1e-8f)) : 0.f;
        e += __shfl_xor(e, 1, 16);
        e += __shfl_xor(e, 2, 16);
        e += __shfl_xor(e, 4, 16);
        e += __shfl_xor(e, 8, 16);
        if (c == 0) {
            float prev = (it == 0) ? 0.f : ytacc[row];
            ytacc[row] = prev + e;
        }
    }

    // ---- colsum for next iteration
    __syncthreads();
    yred[0][t] = (c < 10) ? xn : 0.f;
    __syncthreads();
    if (t < 10) {
        float sc = 0.f;
#pragma unroll
        for (int rr = 0; rr < 16; ++rr) sc += yred[0][t + rr * 16];
        atomicAdd(&Scol[(it + 1) * 80 + pl * 16 + t], sc);
    }
}

// ---------------------------------------------------------------------------
// MFMA MLP (layers 1+2, all levels). 256 blocks x 4 waves.
// ---------------------------------------------------------------------------
__global__ __launch_bounds__(256) void mlp_mfma_kernel(const __half* __restrict__ Xs16f,
                                                       const __half* __restrict__ W1f,
                                                       const __half* __restrict__ W2f,
                                                       const float* __restrict__ b1,
                                                       const float* __restrict__ b2,
                                                       float* __restrict__ H2)
{
    __shared__ char h1s[4][16 * 384];
    __shared__ float b1s[160];
    __shared__ float b2s[80];
    const int t = threadIdx.x;
    const int lane = t & 63, wave = t >> 6;
    const int fr = lane & 15, g = lane >> 4;
    const int lvl = blockIdx.x >> 6;
    const int rb = (blockIdx.x & 63) * 4 + wave;

    if (t < 160) b1s[t] = (t < 150) ? b1[t] : 0.f;
    else if (t < 240) b2s[t - 160] = (t < 235) ? b2[t - 160] : 0.f;
    __syncthreads();

    const __half* Abase = Xs16f + (size_t)lvl * 1310720 + (size_t)rb * 5120;
    f32x4 acc1[10];
#pragma unroll
    for (int j = 0; j < 10; ++j) acc1[j] = (f32x4){0.f, 0.f, 0.f, 0.f};
#pragma unroll
    for (int s = 0; s < 10; ++s) {
        f16x8 a = *(const f16x8*)(Abase + s * 512 + lane * 8);
#pragma unroll
        for (int j = 0; j < 10; ++j) {
            f16x8 b = *(const f16x8*)(W1f + (s * 10 + j) * 512 + lane * 8);
            acc1[j] = __builtin_amdgcn_mfma_f32_16x16x32_f16(a, b, acc1[j], 0, 0, 0);
        }
    }
    char* hw = h1s[wave];
#pragma unroll
    for (int j = 0; j < 10; ++j) {
#pragma unroll
        for (int q = 0; q < 4; ++q) {
            const int row = g * 4 + q;
            const int col = j * 16 + fr;
            float v = fmaxf(acc1[j][q] + b1s[col], 0.f);
            *(__half*)(hw + row * 384 + ((col * 2) ^ ((row & 7) << 4))) = __float2half(v);
        }
    }
    __syncthreads();

    f32x4 acc2[5];
#pragma unroll
    for (int j = 0; j < 5; ++j) acc2[j] = (f32x4){0.f, 0.f, 0.f, 0.f};
#pragma unroll
    for (int s = 0; s < 5; ++s) {
        f16x8 a = *(const f16x8*)(hw + fr * 384 + ((s * 64 + g * 16) ^ ((fr & 7) << 4)));
#pragma unroll
        for (int j = 0; j < 5; ++j) {
            f16x8 b = *(const f16x8*)(W2f + (s * 5 + j) * 512 + lane * 8);
            acc2[j] = __builtin_amdgcn_mfma_f32_16x16x32_f16(a, b, acc2[j], 0, 0, 0);
        }
    }
#pragma unroll
    for (int j = 0; j < 5; ++j) {
        const int col = j * 16 + fr;
        if (col < 75) {
#pragma unroll
            for (int q = 0; q < 4; ++q) {
                const int row = rb * 16 + g * 4 + q;
                float v = fmaxf(acc2[j][q] + b2s[col], 0.f);
                H2[(size_t)row * 300 + lvl * 75 + col] = v;
            }
        }
    }
}

// ---------------------------------------------------------------------------
// Final: y_pred = H2 @ w3 + b3; y_true = ytacc/30; labelled_mask
// ---------------------------------------------------------------------------
__global__ __launch_bounds__(256) void final_kernel(const float* __restrict__ H2,
                                                    const float* __restrict__ w3,
                                                    const float* __restrict__ b3,
                                                    const float* __restrict__ ytacc,
                                                    float* __restrict__ out)
{
    __shared__ float w[300];
    const int t = threadIdx.x;
    const int b = blockIdx.x * 256 + t;
    for (int i = t; i < 300; i += 256) w[i] = w3[i];
    __syncthreads();
    float acc = b3[0];
    const float4* row = (const float4*)(H2 + (size_t)b * 300);
    for (int k4 = 0; k4 < 75; ++k4) {
        float4 v = row[k4];
        acc += v.x * w[k4 * 4] + v.y * w[k4 * 4 + 1] + v.z * w[k4 * 4 + 2] + v.w * w[k4 * 4 + 3];
    }
    out[b] = acc;
    out[4096 + b] = ytacc[b] * (1.0f / 30.0f);
    out[2 * 4096 + b] = (b < 2048) ? 1.0f : 0.0f;
}

// ---------------------------------------------------------------------------
extern "C" void kernel_launch(void* const* d_in, const int* in_sizes, int n_in,
                              void* d_out, int out_size, void* d_ws, size_t ws_size,
                              hipStream_t stream)
{
    (void)in_sizes; (void)n_in; (void)out_size;

    const float* feats[4] = {(const float*)d_in[0], (const float*)d_in[1],
                             (const float*)d_in[2], (const float*)d_in[3]};
    const float* embedds = (const float*)d_in[4];
    const int* labels = (const int*)d_in[6];
    const float* lsw[4] = {(const float*)d_in[7], (const float*)d_in[9],
                           (const float*)d_in[11], (const float*)d_in[13]};
    const float* lsb[4] = {(const float*)d_in[8], (const float*)d_in[10],
                           (const float*)d_in[12], (const float*)d_in[14]};
    const float* w1 = (const float*)d_in[15];
    const float* b1 = (const float*)d_in[16];
    const float* w2 = (const float*)d_in[17];
    const float* b2 = (const float*)d_in[18];
    const float* w3 = (const float*)d_in[19];
    const float* b3 = (const float*)d_in[20];

    // fused: 5 A4 slices (40MB) + 5 A16f slices (160MB); else 1+1
    const bool fused = ws_size >= 256000000ULL;
    const size_t A4_BYTES  = fused ? 41943040ULL : 8388608ULL;
    const size_t A16_BYTES = fused ? 167772160ULL : 33554432ULL;

    char* ws = (char*)d_ws;
    uchar* A4       = (uchar*)(ws);
    __half* A16f    = (__half*)(ws + A4_BYTES);
    char* base      = ws + A4_BYTES + A16_BYTES;
    __half* N16all  = (__half*)(base);                //  8388608
    uchar* Xt8      = (uchar*)(base + 8388608);       //  2 x 327680
    float* X32      = (float*)(base + 9043968);       //  2 x 819200
    __half* Xs16f   = (__half*)(base + 10682368);     //  10485760
    float* H2       = (float*)(base + 21168128);      //  4915200
    float* ytacc    = (float*)(base + 26083328);      //  16384
    float* partials = (float*)(base + 26099712);      //  20480
    float* scal     = (float*)(base + 26120192);      //  256
    float* Scol     = (float*)(base + 26120448);      //  16384
    __half* W1f     = (__half*)(base + 26136832);     //  102400
    __half* W2f     = (__half*)(base + 26239232);     //  25600
    float* pooled   = (float*)(base + 26264832);      //  15728640

    uchar* Xt8b[2] = {Xt8, Xt8 + 327680};
    float* X32b[2] = {X32, X32 + 204800};
    float* out = (float*)d_out;

    auto run_iters = [&](const uchar* Ab4, int pbase, int nprob) {
        init_kernel<<<1280, 256, 0, stream>>>(labels, Xt8b[0], Xt8b[1], X32b[0], Scol);
        for (int it = 0; it < 30; ++it) {
            const int i = it & 1, o = i ^ 1;
            gtg8_kernel<<<nprob * 256, 256, 0, stream>>>(
                Ab4, Xt8b[i], Xt8b[o], X32b[i], X32b[o], Xs16f, ytacc, Scol, it, pbase);
        }
    };

    wfrag_kernel<<<250, 256, 0, stream>>>(w1, w2, W1f, W2f);
    hipMemsetAsync(Xs16f, 0, 10485760, stream);

    // ---- prep: pooled -> N16all (all problems), 3 dispatches
    pool_all_kernel<<<15360, 256, 0, stream>>>(feats[0], feats[1], feats[2], feats[3], pooled);
    lsn_all_kernel<<<16384, 128, 0, stream>>>(pooled,
        lsw[0], lsb[0], lsw[1], lsb[1], lsw[2], lsb[2], lsw[3], lsb[3], N16all);
    norm512_kernel<<<4096, 256, 0, stream>>>(embedds, N16all);

    if (fused) {
        a_gemm_all<<<5 * 1024, 256, 0, stream>>>(N16all, A16f, partials, 0);
        mean_all_kernel<<<5, 256, 0, stream>>>(partials, scal);
        abar4_all_kernel<<<5 * 4096, 256, 0, stream>>>(A16f, A4, scal);
        run_iters(A4, 0, 5);
    } else {
        for (int p = 0; p < 5; ++p) {
            a_gemm_all<<<1024, 256, 0, stream>>>(N16all, A16f, partials, p);
            mean_all_kernel<<<1, 256, 0, stream>>>(partials, scal);
            abar4_all_kernel<<<4096, 256, 0, stream>>>(A16f, A4, scal);
            run_iters(A4, p, 1);
        }
    }

    mlp_mfma_kernel<<<256, 256, 0, stream>>>(Xs16f, W1f, W2f, b1, b2, H2);
    final_kernel<<<16, 256, 0, stream>>>(H2, w3, b3, ytacc, out);
}

// Round 14
// 790.083 us; speedup vs baseline: 1.0021x; 1.0021x over previous
//
#include <hip/hip_runtime.h>
#include <hip/hip_fp16.h>

typedef _Float16 f16x8 __attribute__((ext_vector_type(8)));
typedef float f32x4 __attribute__((ext_vector_type(4)));
typedef unsigned char uchar;

static __device__ __forceinline__ long long mk64(unsigned lo, unsigned hi)
{
    return (long long)(((unsigned long long)hi << 32) | (unsigned long long)lo);
}

// fragment-layout offset for X8 (B-operand): class c, row j
static __device__ __forceinline__ int xfrag_off(int c, int j)
{
    return (j >> 6) * 1024 + (((j >> 3) & 3) * 16 + c) * 16 + ((j >> 5) & 1) * 8 + (j & 7);
}

// fragment-layout offset (halves) for Xs16f (A-operand): row (0..4095), k (0..319)
static __device__ __forceinline__ int xsfrag_off(int row, int k)
{
    return (row >> 4) * 5120 + (k >> 5) * 512 + (((k >> 3) & 3) * 16 + (row & 15)) * 8 + (k & 7);
}

// nibble codes -> fp8 e4m3 bytes of k/16 (exact): LUT via v_perm
#define T03 0x24201800u
#define T47 0x2E2C2A28u
#define T8B 0x33323130u
#define TCF 0x37363534u

static __device__ __forceinline__ void expand4(unsigned w, unsigned& o0, unsigned& o1)
{
    unsigned even = w & 0x0F0F0F0Fu;
    unsigned odd  = (w >> 4) & 0x0F0F0F0Fu;
    unsigned i_lo = __builtin_amdgcn_perm(odd, even, 0x05010400u);
    unsigned i_hi = __builtin_amdgcn_perm(odd, even, 0x07030602u);
    {
        unsigned i3 = i_lo & 0x07070707u;
        unsigned ta = __builtin_amdgcn_perm(T47, T03, i3);
        unsigned tb = __builtin_amdgcn_perm(TCF, T8B, i3);
        unsigned m  = ((i_lo >> 3) & 0x01010101u) * 0xFFu;
        o0 = ta ^ ((ta ^ tb) & m);
    }
    {
        unsigned i3 = i_hi & 0x07070707u;
        unsigned ta = __builtin_amdgcn_perm(T47, T03, i3);
        unsigned tb = __builtin_amdgcn_perm(TCF, T8B, i3);
        unsigned m  = ((i_hi >> 3) & 0x01010101u) * 0xFFu;
        o1 = ta ^ ((ta ^ tb) & m);
    }
}

// ---------------------------------------------------------------------------
// COALESCED pool, all levels, one dispatch. Block = one (level,row).
// Lane t reads float4 #(i*256+t) of the row (4 KB contiguous per wave-iter);
// a channel's float4s land in 16 (S2=64) or 4 (S2=16) consecutive lanes;
// shfl_xor group-reduce, leader writes the mean.
// ---------------------------------------------------------------------------
template <int NITER, int S2>
static __device__ __forceinline__ void pool_row(const float4* __restrict__ src,
                                                float* __restrict__ dst, int t)
{
#pragma unroll
    for (int i = 0; i < NITER; ++i) {
        float4 v = src[i * 256 + t];
        float s = v.x + v.y + v.z + v.w;
        if (S2 == 64) {
            s += __shfl_xor(s, 1, 16);
            s += __shfl_xor(s, 2, 16);
            s += __shfl_xor(s, 4, 16);
            s += __shfl_xor(s, 8, 16);
            if ((t & 15) == 0) dst[i * 16 + (t >> 4)] = s * (1.0f / 64.f);
        } else {
            s += __shfl_xor(s, 1, 4);
            s += __shfl_xor(s, 2, 4);
            if ((t & 3) == 0) dst[i * 64 + (t >> 2)] = s * (1.0f / 16.f);
        }
    }
}

__global__ __launch_bounds__(256) void pool_all_kernel(
    const float* __restrict__ f0, const float* __restrict__ f1,
    const float* __restrict__ f2, const float* __restrict__ f3,
    float* __restrict__ pooled)
{
    const int b = blockIdx.x;               // 16384 = 4 levels x 4096 rows
    const int p = b >> 12, row = b & 4095;
    const int t = threadIdx.x;
    switch (p) {
        case 0:
            pool_row<4, 64>((const float4*)(f0 + (size_t)row * 4096),
                            pooled + (size_t)row * 64, t);
            break;
        case 1:
            pool_row<8, 64>((const float4*)(f1 + (size_t)row * 8192),
                            pooled + 262144 + (size_t)row * 128, t);
            break;
        case 2:
            pool_row<4, 16>((const float4*)(f2 + (size_t)row * 4096),
                            pooled + 786432 + (size_t)row * 256, t);
            break;
        default:
            pool_row<8, 16>((const float4*)(f3 + (size_t)row * 8192),
                            pooled + 1835008 + (size_t)row * 512, t);
            break;
    }
}

// ---------------------------------------------------------------------------
// Linear+ReLU+row-normalize for all 4 levels in one dispatch.
// Grid 16384 blocks x 128 threads; p = blk>>12, row = blk&4095.
// ---------------------------------------------------------------------------
__global__ __launch_bounds__(128) void lsn_all_kernel(
    const float* __restrict__ pooled,
    const float* __restrict__ lw0, const float* __restrict__ lb0,
    const float* __restrict__ lw1, const float* __restrict__ lb1,
    const float* __restrict__ lw2, const float* __restrict__ lb2,
    const float* __restrict__ lw3, const float* __restrict__ lb3,
    __half* __restrict__ N16all)
{
    __shared__ float pl[512];
    __shared__ float red2[2];
    const int t = threadIdx.x;
    const int p = blockIdx.x >> 12;
    const int row = blockIdx.x & 4095;
    const float* w; const float* b; int C, pOff;
    switch (p) {
        case 0:  w = lw0; b = lb0; C = 64;  pOff = 0;       break;
        case 1:  w = lw1; b = lb1; C = 128; pOff = 262144;  break;
        case 2:  w = lw2; b = lb2; C = 256; pOff = 786432;  break;
        default: w = lw3; b = lb3; C = 512; pOff = 1835008; break;
    }
    for (int k = t; k < C; k += 128) pl[k] = pooled[pOff + (size_t)row * C + k];
    __syncthreads();
    float acc = b[t];
    for (int k = 0; k < C; ++k) acc = fmaf(pl[k], w[(size_t)k * 128 + t], acc);
    float v = fmaxf(acc, 0.f);
    float ss = v * v;
    for (int off = 32; off > 0; off >>= 1) ss += __shfl_down(ss, off, 64);
    if ((t & 63) == 0) red2[t >> 6] = ss;
    __syncthreads();
    float inv = 1.0f / fmaxf(sqrtf(red2[0] + red2[1]), 1e-12f);
    N16all[(size_t)p * 524288 + (size_t)row * 128 + t] = __float2half(v * inv);
}

// ---------------------------------------------------------------------------
// Normalize embedds rows (d=512) -> N16all + 2097152
// ---------------------------------------------------------------------------
__global__ __launch_bounds__(256) void norm512_kernel(const float* __restrict__ E,
                                                      __half* __restrict__ N16all)
{
    __shared__ float red4[4];
    const int b = blockIdx.x, t = threadIdx.x;
    float2 v = *(const float2*)(E + (size_t)b * 512 + t * 2);
    float ss = v.x * v.x + v.y * v.y;
    for (int off = 32; off > 0; off >>= 1) ss += __shfl_down(ss, off, 64);
    if ((t & 63) == 0) red4[t >> 6] = ss;
    __syncthreads();
    float inv = 1.0f / fmaxf(sqrtf(red4[0] + red4[1] + red4[2] + red4[3]), 1e-12f);
    __half2 o;
    o.x = __float2half(v.x * inv);
    o.y = __float2half(v.y * inv);
    *(__half2*)(N16all + 2097152 + (size_t)b * 512 + t * 2) = o;
}

// ---------------------------------------------------------------------------
// All-problem MFMA GEMM. Grid pcount*1024; p = pbase + blk>>10, runtime K.
// ---------------------------------------------------------------------------
__global__ __launch_bounds__(256) void a_gemm_all(const __half* __restrict__ N16all,
                                                  __half* __restrict__ A16f,
                                                  float* __restrict__ partials,
                                                  int pbase)
{
    __shared__ __half smem[16384];   // As(8192) | Bs(8192); reused as Cst
    __shared__ float reds[4];
    __half* As = smem;
    __half* Bs = smem + 8192;
    char* Cb = (char*)smem;
    const int t = threadIdx.x;
    const int lane = t & 63, wave = t >> 6;
    const int lp = blockIdx.x >> 10;
    const int p = pbase + lp;
    const int blk = blockIdx.x & 1023;
    const int K = (p == 4) ? 512 : 128;
    const __half* N16 = N16all + ((p == 4) ? 2097152u : (unsigned)p * 524288u);
    const int bx = blk & 31, by = blk >> 5;
    const int wr = wave >> 1, wc = wave & 1;
    const int fr = lane & 15;
    const int g = lane >> 4;
    const int r0 = by * 128, c0 = bx * 128;
    const int sr = t >> 3;
    const int sc = t & 7;

    f32x4 acc[4][4];
#pragma unroll
    for (int i = 0; i < 4; ++i)
#pragma unroll
        for (int j = 0; j < 4; ++j) acc[i][j] = (f32x4){0.f, 0.f, 0.f, 0.f};

    for (int kt = 0; kt < (K >> 6); ++kt) {
        const int kb = kt * 64;
        __syncthreads();
#pragma unroll
        for (int pp = 0; pp < 4; ++pp) {
            const int r = pp * 32 + sr;
            uint4 va = *(const uint4*)(N16 + (size_t)(r0 + r) * K + kb + sc * 8);
            uint4 vb = *(const uint4*)(N16 + (size_t)(c0 + r) * K + kb + sc * 8);
            const int d = r * 64 + ((((sc * 16) ^ ((r & 7) << 4))) >> 1);
            *(uint4*)&As[d] = va;
            *(uint4*)&Bs[d] = vb;
        }
        __syncthreads();
#pragma unroll
        for (int ks = 0; ks < 2; ++ks) {
            const int ko = ((ks * 64 + g * 16) ^ ((fr & 7) << 4)) >> 1;
            f16x8 af[4], bf[4];
#pragma unroll
            for (int i = 0; i < 4; ++i) {
                af[i] = *(const f16x8*)&As[(wr * 64 + i * 16 + fr) * 64 + ko];
                bf[i] = *(const f16x8*)&Bs[(wc * 64 + i * 16 + fr) * 64 + ko];
            }
#pragma unroll
            for (int i = 0; i < 4; ++i)
#pragma unroll
                for (int j = 0; j < 4; ++j)
                    acc[i][j] = __builtin_amdgcn_mfma_f32_16x16x32_f16(af[i], bf[j], acc[i][j], 0, 0, 0);
        }
    }
    __syncthreads();

    float lsum = 0.f;
    const int r4 = g * 4;
#pragma unroll
    for (int i = 0; i < 4; ++i) {
#pragma unroll
        for (int q = 0; q < 4; ++q) {
            const int lr = wr * 64 + i * 16 + r4 + q;
            const int row = r0 + lr;
#pragma unroll
            for (int j = 0; j < 4; ++j) {
                const int lc2 = wc * 64 + j * 16 + fr;
                const int col = c0 + lc2;
                float v = fminf(fmaxf(acc[i][j][q], 0.f), 1.f);
                if (row == col) v = 0.f;
                lsum += v;
                *(__half*)(Cb + lr * 256 + ((lc2 * 2) ^ ((lr & 7) << 4))) = __float2half(v);
            }
        }
    }
    __syncthreads();

#pragma unroll
    for (int pp = 0; pp < 4; ++pp) {
        const int rbl2 = pp * 4 + (t >> 6);
        const int rbl = rbl2 >> 1, ks2l = rbl2 & 1;
        const int l = t & 63;
        const int lr = rbl * 16 + (l & 15);
        const int e0 = ks2l * 64 + (l >> 4) * 8;
        uint4 v0 = *(const uint4*)(Cb + lr * 256 + ((e0 * 2) ^ ((lr & 7) << 4)));
        uint4 v1 = *(const uint4*)(Cb + lr * 256 + (((e0 + 32) * 2) ^ ((lr & 7) << 4)));
        const size_t rb = (size_t)(by * 8 + rbl);
        const size_t ks2 = (size_t)(bx * 2 + ks2l);
        char* dst = (char*)A16f + (size_t)lp * 33554432 + rb * 131072 + ks2 * 2048 + l * 32;
        *(uint4*)dst = v0;
        *(uint4*)(dst + 16) = v1;
    }

    for (int off = 32; off > 0; off >>= 1) lsum += __shfl_down(lsum, off, 64);
    if (lane == 0) reds[wave] = lsum;
    __syncthreads();
    if (t == 0) partials[lp * 1024 + blk] = reds[0] + reds[1] + reds[2] + reds[3];
}

// ---------------------------------------------------------------------------
// mean per problem: block lp reduces partials[lp][0..1023] -> scal[lp]
// ---------------------------------------------------------------------------
__global__ __launch_bounds__(256) void mean_all_kernel(const float* __restrict__ partials,
                                                       float* __restrict__ scal)
{
    __shared__ float red[4];
    const int t = threadIdx.x, lp = blockIdx.x;
    float s = 0.f;
    for (int i = t; i < 1024; i += 256) s += partials[lp * 1024 + i];
    for (int off = 32; off > 0; off >>= 1) s += __shfl_down(s, off, 64);
    if ((t & 63) == 0) red[t >> 6] = s;
    __syncthreads();
    if (t == 0) scal[lp] = (red[0] + red[1] + red[2] + red[3]) * (1.0f / 16777216.0f);
}

// ---------------------------------------------------------------------------
// Quantize to 4-bit codes round(16*(a<mean?0:a)), linear frag order.
// Grid pcount*4096; lp = blk>>12.
// ---------------------------------------------------------------------------
__global__ __launch_bounds__(256) void abar4_all_kernel(const __half* __restrict__ A16f,
                                                        uchar* __restrict__ A4,
                                                        const float* __restrict__ scal)
{
    const int lp = blockIdx.x >> 12;
    const float mean = scal[lp];
    const size_t i = (size_t)(blockIdx.x & 4095) * 256 + threadIdx.x;
    const __half* src = A16f + (size_t)lp * 16777216 + i * 16;
    uint4 u0 = *(const uint4*)(src);
    uint4 u1 = *(const uint4*)(src + 8);
    __half h[16];
    *(uint4*)h = u0;
    *(uint4*)(h + 8) = u1;
    unsigned d0 = 0, d1 = 0;
#pragma unroll
    for (int k = 0; k < 8; ++k) {
        float a = __half2float(h[k]);
        float v = (a < mean) ? 0.f : a;
        unsigned n = (unsigned)fminf(v * 16.f + 0.5f, 15.f);
        d0 |= n << (4 * k);
    }
#pragma unroll
    for (int k = 0; k < 8; ++k) {
        float a = __half2float(h[8 + k]);
        float v = (a < mean) ? 0.f : a;
        unsigned n = (unsigned)fminf(v * 16.f + 0.5f, 15.f);
        d1 |= n << (4 * k);
    }
    uint2 o; o.x = d0; o.y = d1;
    *(uint2*)(A4 + (size_t)lp * 8388608 + i * 8) = o;
}

// ---------------------------------------------------------------------------
// X0 init + Scol init (blocks 0..30) + label histogram (block 0)
// ---------------------------------------------------------------------------
__global__ __launch_bounds__(256) void init_kernel(const int* __restrict__ labels,
                                                   uchar* __restrict__ X8_0,
                                                   uchar* __restrict__ X8_1,
                                                   float* __restrict__ X32,
                                                   float* __restrict__ Scol)
{
    __shared__ int hist[16];
    const int blk = blockIdx.x;
    const int t = threadIdx.x;
    const int idx = blk * 256 + t;   // 5*16*4096 = 327680
    const int p = idx >> 16;
    const int rem = idx & 65535;
    const int c = rem >> 12, j = rem & 4095;
    float v;
    if (c >= 10) v = 0.f;
    else if (j < 2048) v = (labels[j] == c) ? 1.0f : 0.0f;
    else v = 0.1f;
    unsigned pk = __builtin_amdgcn_cvt_pk_fp8_f32(v, v, 0, false);
    X8_0[(size_t)p * 65536 + xfrag_off(c, j)] = (uchar)(pk & 0xff);
    if (c >= 10) X8_1[(size_t)p * 65536 + xfrag_off(c, j)] = 0;
    if (c < 10) X32[((size_t)p * 4096 + j) * 10 + c] = v;

    if (blk == 0) {
        if (t < 16) hist[t] = 0;
        __syncthreads();
        for (int i = t; i < 2048; i += 256) atomicAdd(&hist[labels[i]], 1);
        __syncthreads();
        if (t < 80) {
            const int pp = t >> 4, cc = t & 15;
            Scol[pp * 16 + cc] = (cc < 10) ? ((float)hist[cc] + 204.8f) : 0.f;
        }
    } else if (blk <= 30) {
        if (t < 80) Scol[blk * 80 + t] = 0.f;
    }
}

// ---------------------------------------------------------------------------
// Pack w1 (300x150) and w2 (150x75) into fragment-major fp16 B-operand form.
// ---------------------------------------------------------------------------
__global__ __launch_bounds__(256) void wfrag_kernel(const float* __restrict__ w1,
                                                    const float* __restrict__ w2,
                                                    __half* __restrict__ W1f,
                                                    __half* __restrict__ W2f)
{
    int idx = blockIdx.x * 256 + threadIdx.x;   // 51200 + 12800 = 64000
    if (idx < 51200) {
        const int frag = idx >> 9, e9 = idx & 511;
        const int s = frag / 10, j = frag % 10;
        const int g = e9 >> 7, fr = (e9 >> 3) & 15, e = e9 & 7;
        const int k = s * 32 + g * 8 + e, n = j * 16 + fr;
        const float v = (k < 300 && n < 150) ? w1[(size_t)k * 150 + n] : 0.f;
        W1f[idx] = __float2half(v);
    } else if (idx < 64000) {
        const int i2 = idx - 51200;
        const int frag = i2 >> 9, e9 = i2 & 511;
        const int s = frag / 5, j = frag % 5;
        const int g = e9 >> 7, fr = (e9 >> 3) & 15, e = e9 & 7;
        const int k = s * 32 + g * 8 + e, n = j * 16 + fr;
        const float v = (k < 150 && n < 75) ? w2[(size_t)k * 75 + n] : 0.f;
        W2f[i2] = __float2half(v);
    }
}

// ---------------------------------------------------------------------------
// One GTG iteration: 4-bit A expanded in-register to fp8 (LUT), fp8 MFMA.
// 5 blocks/CU residency (min 5 waves/EU).
// ---------------------------------------------------------------------------
__global__ __launch_bounds__(256, 5) void gtg8_kernel(
    const uchar* __restrict__ A4f,
    const uchar* __restrict__ X8i, uchar* __restrict__ X8o,
    const float* __restrict__ X32i, float* __restrict__ X32o,
    __half* __restrict__ Xs16f, float* __restrict__ ytacc,
    float* __restrict__ Scol, int it, int pbase)
{
    __shared__ float yred[4][256];
    const int t = threadIdx.x;
    const int lane = t & 63, wave = t >> 6;
    const int p = pbase + (blockIdx.x >> 8);
    const int pl = p - pbase;
    const int rb = blockIdx.x & 255;

    const uchar* Ab = A4f + (size_t)pl * 8388608 + (size_t)rb * 32768
                    + wave * 8192 + lane * 8;
    const uchar* Xb = X8i + (size_t)p * 65536 + wave * 16384 + lane * 16;

    f32x4 acc0 = {0.f, 0.f, 0.f, 0.f};
    f32x4 acc1 = {0.f, 0.f, 0.f, 0.f};
#pragma unroll
    for (int u = 0; u < 16; ++u) {
        uint2 a4 = *(const uint2*)(Ab + u * 512);
        uint4 bv = *(const uint4*)(Xb + u * 1024);
        unsigned e00, e01, e10, e11;
        expand4(a4.x, e00, e01);
        expand4(a4.y, e10, e11);
        acc0 = __builtin_amdgcn_mfma_f32_16x16x32_fp8_fp8(
            mk64(e00, e01), mk64(bv.x, bv.y), acc0, 0, 0, 0);
        acc1 = __builtin_amdgcn_mfma_f32_16x16x32_fp8_fp8(
            mk64(e10, e11), mk64(bv.z, bv.w), acc1, 0, 0, 0);
    }
    {
        const int r4 = (lane >> 4) * 4;
        const int fr = lane & 15;
#pragma unroll
        for (int q = 0; q < 4; ++q)
            yred[wave][(r4 + q) * 16 + fr] = acc0[q] + acc1[q];
    }
    __syncthreads();

    // ---- update phase: thread t -> row r=t>>4, class c=t&15
    const int r = t >> 4, c = t & 15;
    const int row = rb * 16 + r;
    const float T = yred[0][t] + yred[1][t] + yred[2][t] + yred[3][t];
    const float y = Scol[it * 80 + pl * 16 + c] - T;
    const float x = (c < 10) ? X32i[((size_t)p * 4096 + row) * 10 + c] : 0.f;
    const float m = x * y;
    float s = m;
    s += __shfl_xor(s, 1, 16);
    s += __shfl_xor(s, 2, 16);
    s += __shfl_xor(s, 4, 16);
    s += __shfl_xor(s, 8, 16);
    const float dv = m / (s + 1e-8f);
    const float xn = x + dv;
    if (c < 10) {
        X32o[((size_t)p * 4096 + row) * 10 + c] = xn;
        unsigned pk = __builtin_amdgcn_cvt_pk_fp8_f32(xn, xn, 0, false);
        X8o[(size_t)p * 65536 + xfrag_off(c, row)] = (uchar)(pk & 0xff);
        if (p < 4) {
            const int k = c * 30 + it;
            Xs16f[(size_t)p * 1310720 + xsfrag_off(row, k)] = __float2half(xn);
        }
    }
    if (p == 4) {
        float e = (c < 10) ? (-dv * logf(dv + 1e-8f)) : 0.f;
        e += __shfl_xor(e, 1, 16);
        e += __shfl_xor(e, 2, 16);
        e += __shfl_xor(e, 4, 16);
        e += __shfl_xor(e, 8, 16);
        if (c == 0) {
            float prev = (it == 0) ? 0.f : ytacc[row];
            ytacc[row] = prev + e;
        }
    }

    // ---- colsum for next iteration
    __syncthreads();
    yred[0][t] = (c < 10) ? xn : 0.f;
    __syncthreads();
    if (t < 10) {
        float sc = 0.f;
#pragma unroll
        for (int rr = 0; rr < 16; ++rr) sc += yred[0][t + rr * 16];
        atomicAdd(&Scol[(it + 1) * 80 + pl * 16 + t], sc);
    }
}

// ---------------------------------------------------------------------------
// MFMA MLP (layers 1+2, all levels). 256 blocks x 4 waves.
// ---------------------------------------------------------------------------
__global__ __launch_bounds__(256) void mlp_mfma_kernel(const __half* __restrict__ Xs16f,
                                                       const __half* __restrict__ W1f,
                                                       const __half* __restrict__ W2f,
                                                       const float* __restrict__ b1,
                                                       const float* __restrict__ b2,
                                                       float* __restrict__ H2)
{
    __shared__ char h1s[4][16 * 384];
    __shared__ float b1s[160];
    __shared__ float b2s[80];
    const int t = threadIdx.x;
    const int lane = t & 63, wave = t >> 6;
    const int fr = lane & 15, g = lane >> 4;
    const int lvl = blockIdx.x >> 6;
    const int rb = (blockIdx.x & 63) * 4 + wave;

    if (t < 160) b1s[t] = (t < 150) ? b1[t] : 0.f;
    else if (t < 240) b2s[t - 160] = (t < 235) ? b2[t - 160] : 0.f;
    __syncthreads();

    const __half* Abase = Xs16f + (size_t)lvl * 1310720 + (size_t)rb * 5120;
    f32x4 acc1[10];
#pragma unroll
    for (int j = 0; j < 10; ++j) acc1[j] = (f32x4){0.f, 0.f, 0.f, 0.f};
#pragma unroll
    for (int s = 0; s < 10; ++s) {
        f16x8 a = *(const f16x8*)(Abase + s * 512 + lane * 8);
#pragma unroll
        for (int j = 0; j < 10; ++j) {
            f16x8 b = *(const f16x8*)(W1f + (s * 10 + j) * 512 + lane * 8);
            acc1[j] = __builtin_amdgcn_mfma_f32_16x16x32_f16(a, b, acc1[j], 0, 0, 0);
        }
    }
    char* hw = h1s[wave];
#pragma unroll
    for (int j = 0; j < 10; ++j) {
#pragma unroll
        for (int q = 0; q < 4; ++q) {
            const int row = g * 4 + q;
            const int col = j * 16 + fr;
            float v = fmaxf(acc1[j][q] + b1s[col], 0.f);
            *(__half*)(hw + row * 384 + ((col * 2) ^ ((row & 7) << 4))) = __float2half(v);
        }
    }
    __syncthreads();

    f32x4 acc2[5];
#pragma unroll
    for (int j = 0; j < 5; ++j) acc2[j] = (f32x4){0.f, 0.f, 0.f, 0.f};
#pragma unroll
    for (int s = 0; s < 5; ++s) {
        f16x8 a = *(const f16x8*)(hw + fr * 384 + ((s * 64 + g * 16) ^ ((fr & 7) << 4)));
#pragma unroll
        for (int j = 0; j < 5; ++j) {
            f16x8 b = *(const f16x8*)(W2f + (s * 5 + j) * 512 + lane * 8);
            acc2[j] = __builtin_amdgcn_mfma_f32_16x16x32_f16(a, b, acc2[j], 0, 0, 0);
        }
    }
#pragma unroll
    for (int j = 0; j < 5; ++j) {
        const int col = j * 16 + fr;
        if (col < 75) {
#pragma unroll
            for (int q = 0; q < 4; ++q) {
                const int row = rb * 16 + g * 4 + q;
                float v = fmaxf(acc2[j][q] + b2s[col], 0.f);
                H2[(size_t)row * 300 + lvl * 75 + col] = v;
            }
        }
    }
}

// ---------------------------------------------------------------------------
// Final: y_pred = H2 @ w3 + b3; y_true = ytacc/30; labelled_mask
// ---------------------------------------------------------------------------
__global__ __launch_bounds__(256) void final_kernel(const float* __restrict__ H2,
                                                    const float* __restrict__ w3,
                                                    const float* __restrict__ b3,
                                                    const float* __restrict__ ytacc,
                                                    float* __restrict__ out)
{
    __shared__ float w[300];
    const int t = threadIdx.x;
    const int b = blockIdx.x * 256 + t;
    for (int i = t; i < 300; i += 256) w[i] = w3[i];
    __syncthreads();
    float acc = b3[0];
    const float4* row = (const float4*)(H2 + (size_t)b * 300);
    for (int k4 = 0; k4 < 75; ++k4) {
        float4 v = row[k4];
        acc += v.x * w[k4 * 4] + v.y * w[k4 * 4 + 1] + v.z * w[k4 * 4 + 2] + v.w * w[k4 * 4 + 3];
    }
    out[b] = acc;
    out[4096 + b] = ytacc[b] * (1.0f / 30.0f);
    out[2 * 4096 + b] = (b < 2048) ? 1.0f : 0.0f;
}

// ---------------------------------------------------------------------------
extern "C" void kernel_launch(void* const* d_in, const int* in_sizes, int n_in,
                              void* d_out, int out_size, void* d_ws, size_t ws_size,
                              hipStream_t stream)
{
    (void)in_sizes; (void)n_in; (void)out_size;

    const float* feats[4] = {(const float*)d_in[0], (const float*)d_in[1],
                             (const float*)d_in[2], (const float*)d_in[3]};
    const float* embedds = (const float*)d_in[4];
    const int* labels = (const int*)d_in[6];
    const float* lsw[4] = {(const float*)d_in[7], (const float*)d_in[9],
                           (const float*)d_in[11], (const float*)d_in[13]};
    const float* lsb[4] = {(const float*)d_in[8], (const float*)d_in[10],
                           (const float*)d_in[12], (const float*)d_in[14]};
    const float* w1 = (const float*)d_in[15];
    const float* b1 = (const float*)d_in[16];
    const float* w2 = (const float*)d_in[17];
    const float* b2 = (const float*)d_in[18];
    const float* w3 = (const float*)d_in[19];
    const float* b3 = (const float*)d_in[20];

    // fused: 5 A4 slices (40MB) + 5 A16f slices (160MB); else 1+1
    const bool fused = ws_size >= 256000000ULL;
    const size_t A4_BYTES  = fused ? 41943040ULL : 8388608ULL;
    const size_t A16_BYTES = fused ? 167772160ULL : 33554432ULL;

    char* ws = (char*)d_ws;
    uchar* A4       = (uchar*)(ws);
    __half* A16f    = (__half*)(ws + A4_BYTES);
    char* base      = ws + A4_BYTES + A16_BYTES;
    __half* N16all  = (__half*)(base);                //  8388608
    uchar* Xt8      = (uchar*)(base + 8388608);       //  2 x 327680
    float* X32      = (float*)(base + 9043968);       //  2 x 819200
    __half* Xs16f   = (__half*)(base + 10682368);     //  10485760
    float* H2       = (float*)(base + 21168128);      //  4915200
    float* ytacc    = (float*)(base + 26083328);      //  16384
    float* partials = (float*)(base + 26099712);      //  20480
    float* scal     = (float*)(base + 26120192);      //  256
    float* Scol     = (float*)(base + 26120448);      //  16384
    __half* W1f     = (__half*)(base + 26136832);     //  102400
    __half* W2f     = (__half*)(base + 26239232);     //  25600
    float* pooled   = (float*)(base + 26264832);      //  15728640

    uchar* Xt8b[2] = {Xt8, Xt8 + 327680};
    float* X32b[2] = {X32, X32 + 204800};
    float* out = (float*)d_out;

    auto run_iters = [&](const uchar* Ab4, int pbase, int nprob) {
        init_kernel<<<1280, 256, 0, stream>>>(labels, Xt8b[0], Xt8b[1], X32b[0], Scol);
        for (int it = 0; it < 30; ++it) {
            const int i = it & 1, o = i ^ 1;
            gtg8_kernel<<<nprob * 256, 256, 0, stream>>>(
                Ab4, Xt8b[i], Xt8b[o], X32b[i], X32b[o], Xs16f, ytacc, Scol, it, pbase);
        }
    };

    wfrag_kernel<<<250, 256, 0, stream>>>(w1, w2, W1f, W2f);
    hipMemsetAsync(Xs16f, 0, 10485760, stream);

    // ---- prep: pooled -> N16all (all problems)
    pool_all_kernel<<<16384, 256, 0, stream>>>(feats[0], feats[1], feats[2], feats[3], pooled);
    lsn_all_kernel<<<16384, 128, 0, stream>>>(pooled,
        lsw[0], lsb[0], lsw[1], lsb[1], lsw[2], lsb[2], lsw[3], lsb[3], N16all);
    norm512_kernel<<<4096, 256, 0, stream>>>(embedds, N16all);

    if (fused) {
        a_gemm_all<<<5 * 1024, 256, 0, stream>>>(N16all, A16f, partials, 0);
        mean_all_kernel<<<5, 256, 0, stream>>>(partials, scal);
        abar4_all_kernel<<<5 * 4096, 256, 0, stream>>>(A16f, A4, scal);
        run_iters(A4, 0, 5);
    } else {
        for (int p = 0; p < 5; ++p) {
            a_gemm_all<<<1024, 256, 0, stream>>>(N16all, A16f, partials, p);
            mean_all_kernel<<<1, 256, 0, stream>>>(partials, scal);
            abar4_all_kernel<<<4096, 256, 0, stream>>>(A16f, A4, scal);
            run_iters(A4, p, 1);
        }
    }

    mlp_mfma_kernel<<<256, 256, 0, stream>>>(Xs16f, W1f, W2f, b1, b2, H2);
    final_kernel<<<16, 256, 0, stream>>>(H2, w3, b3, ytacc, out);
}

// Round 15
// 789.862 us; speedup vs baseline: 1.0024x; 1.0003x over previous
//
#include <hip/hip_runtime.h>
#include <hip/hip_fp16.h>

typedef _Float16 f16x8 __attribute__((ext_vector_type(8)));
typedef float f32x4 __attribute__((ext_vector_type(4)));
typedef unsigned char uchar;

static __device__ __forceinline__ long long mk64(unsigned lo, unsigned hi)
{
    return (long long)(((unsigned long long)hi << 32) | (unsigned long long)lo);
}

// fragment-layout offset for X8 (B-operand): class c, row j
static __device__ __forceinline__ int xfrag_off(int c, int j)
{
    return (j >> 6) * 1024 + (((j >> 3) & 3) * 16 + c) * 16 + ((j >> 5) & 1) * 8 + (j & 7);
}

// fragment-layout offset (halves) for Xs16f (A-operand): row (0..4095), k (0..319)
static __device__ __forceinline__ int xsfrag_off(int row, int k)
{
    return (row >> 4) * 5120 + (k >> 5) * 512 + (((k >> 3) & 3) * 16 + (row & 15)) * 8 + (k & 7);
}

// nibble codes -> fp8 e4m3 bytes of k/16 (exact): LUT via v_perm
#define T03 0x24201800u
#define T47 0x2E2C2A28u
#define T8B 0x33323130u
#define TCF 0x37363534u

static __device__ __forceinline__ void expand4(unsigned w, unsigned& o0, unsigned& o1)
{
    unsigned even = w & 0x0F0F0F0Fu;
    unsigned odd  = (w >> 4) & 0x0F0F0F0Fu;
    unsigned i_lo = __builtin_amdgcn_perm(odd, even, 0x05010400u);
    unsigned i_hi = __builtin_amdgcn_perm(odd, even, 0x07030602u);
    {
        unsigned i3 = i_lo & 0x07070707u;
        unsigned ta = __builtin_amdgcn_perm(T47, T03, i3);
        unsigned tb = __builtin_amdgcn_perm(TCF, T8B, i3);
        unsigned m  = ((i_lo >> 3) & 0x01010101u) * 0xFFu;
        o0 = ta ^ ((ta ^ tb) & m);
    }
    {
        unsigned i3 = i_hi & 0x07070707u;
        unsigned ta = __builtin_amdgcn_perm(T47, T03, i3);
        unsigned tb = __builtin_amdgcn_perm(TCF, T8B, i3);
        unsigned m  = ((i_hi >> 3) & 0x01010101u) * 0xFFu;
        o1 = ta ^ ((ta ^ tb) & m);
    }
}

// ---------------------------------------------------------------------------
// COALESCED pool with BATCHED loads (high MLP): all NITER float4 loads are
// issued into registers before any reduction, so 4-8 loads are in flight per
// wave instead of 1. Block = one (level,row).
// ---------------------------------------------------------------------------
template <int NITER, int S2>
static __device__ __forceinline__ void pool_row(const float4* __restrict__ src,
                                                float* __restrict__ dst, int t)
{
    float4 v[NITER];
#pragma unroll
    for (int i = 0; i < NITER; ++i) v[i] = src[i * 256 + t];
#pragma unroll
    for (int i = 0; i < NITER; ++i) {
        float s = v[i].x + v[i].y + v[i].z + v[i].w;
        if (S2 == 64) {
            s += __shfl_xor(s, 1, 16);
            s += __shfl_xor(s, 2, 16);
            s += __shfl_xor(s, 4, 16);
            s += __shfl_xor(s, 8, 16);
            if ((t & 15) == 0) dst[i * 16 + (t >> 4)] = s * (1.0f / 64.f);
        } else {
            s += __shfl_xor(s, 1, 4);
            s += __shfl_xor(s, 2, 4);
            if ((t & 3) == 0) dst[i * 64 + (t >> 2)] = s * (1.0f / 16.f);
        }
    }
}

__global__ __launch_bounds__(256) void pool_all_kernel(
    const float* __restrict__ f0, const float* __restrict__ f1,
    const float* __restrict__ f2, const float* __restrict__ f3,
    float* __restrict__ pooled)
{
    const int b = blockIdx.x;               // 16384 = 4 levels x 4096 rows
    const int p = b >> 12, row = b & 4095;
    const int t = threadIdx.x;
    switch (p) {
        case 0:
            pool_row<4, 64>((const float4*)(f0 + (size_t)row * 4096),
                            pooled + (size_t)row * 64, t);
            break;
        case 1:
            pool_row<8, 64>((const float4*)(f1 + (size_t)row * 8192),
                            pooled + 262144 + (size_t)row * 128, t);
            break;
        case 2:
            pool_row<4, 16>((const float4*)(f2 + (size_t)row * 4096),
                            pooled + 786432 + (size_t)row * 256, t);
            break;
        default:
            pool_row<8, 16>((const float4*)(f3 + (size_t)row * 8192),
                            pooled + 1835008 + (size_t)row * 512, t);
            break;
    }
}

// ---------------------------------------------------------------------------
// Linear+ReLU+row-normalize for all 4 levels in one dispatch.
// Grid 16384 blocks x 128 threads; p = blk>>12, row = blk&4095.
// ---------------------------------------------------------------------------
__global__ __launch_bounds__(128) void lsn_all_kernel(
    const float* __restrict__ pooled,
    const float* __restrict__ lw0, const float* __restrict__ lb0,
    const float* __restrict__ lw1, const float* __restrict__ lb1,
    const float* __restrict__ lw2, const float* __restrict__ lb2,
    const float* __restrict__ lw3, const float* __restrict__ lb3,
    __half* __restrict__ N16all)
{
    __shared__ float pl[512];
    __shared__ float red2[2];
    const int t = threadIdx.x;
    const int p = blockIdx.x >> 12;
    const int row = blockIdx.x & 4095;
    const float* w; const float* b; int C, pOff;
    switch (p) {
        case 0:  w = lw0; b = lb0; C = 64;  pOff = 0;       break;
        case 1:  w = lw1; b = lb1; C = 128; pOff = 262144;  break;
        case 2:  w = lw2; b = lb2; C = 256; pOff = 786432;  break;
        default: w = lw3; b = lb3; C = 512; pOff = 1835008; break;
    }
    for (int k = t; k < C; k += 128) pl[k] = pooled[pOff + (size_t)row * C + k];
    __syncthreads();
    float acc = b[t];
    for (int k = 0; k < C; ++k) acc = fmaf(pl[k], w[(size_t)k * 128 + t], acc);
    float v = fmaxf(acc, 0.f);
    float ss = v * v;
    for (int off = 32; off > 0; off >>= 1) ss += __shfl_down(ss, off, 64);
    if ((t & 63) == 0) red2[t >> 6] = ss;
    __syncthreads();
    float inv = 1.0f / fmaxf(sqrtf(red2[0] + red2[1]), 1e-12f);
    N16all[(size_t)p * 524288 + (size_t)row * 128 + t] = __float2half(v * inv);
}

// ---------------------------------------------------------------------------
// Normalize embedds rows (d=512) -> N16all + 2097152
// ---------------------------------------------------------------------------
__global__ __launch_bounds__(256) void norm512_kernel(const float* __restrict__ E,
                                                      __half* __restrict__ N16all)
{
    __shared__ float red4[4];
    const int b = blockIdx.x, t = threadIdx.x;
    float2 v = *(const float2*)(E + (size_t)b * 512 + t * 2);
    float ss = v.x * v.x + v.y * v.y;
    for (int off = 32; off > 0; off >>= 1) ss += __shfl_down(ss, off, 64);
    if ((t & 63) == 0) red4[t >> 6] = ss;
    __syncthreads();
    float inv = 1.0f / fmaxf(sqrtf(red4[0] + red4[1] + red4[2] + red4[3]), 1e-12f);
    __half2 o;
    o.x = __float2half(v.x * inv);
    o.y = __float2half(v.y * inv);
    *(__half2*)(N16all + 2097152 + (size_t)b * 512 + t * 2) = o;
}

// ---------------------------------------------------------------------------
// All-problem MFMA GEMM. Grid pcount*1024; p = pbase + blk>>10, runtime K.
// ---------------------------------------------------------------------------
__global__ __launch_bounds__(256) void a_gemm_all(const __half* __restrict__ N16all,
                                                  __half* __restrict__ A16f,
                                                  float* __restrict__ partials,
                                                  int pbase)
{
    __shared__ __half smem[16384];   // As(8192) | Bs(8192); reused as Cst
    __shared__ float reds[4];
    __half* As = smem;
    __half* Bs = smem + 8192;
    char* Cb = (char*)smem;
    const int t = threadIdx.x;
    const int lane = t & 63, wave = t >> 6;
    const int lp = blockIdx.x >> 10;
    const int p = pbase + lp;
    const int blk = blockIdx.x & 1023;
    const int K = (p == 4) ? 512 : 128;
    const __half* N16 = N16all + ((p == 4) ? 2097152u : (unsigned)p * 524288u);
    const int bx = blk & 31, by = blk >> 5;
    const int wr = wave >> 1, wc = wave & 1;
    const int fr = lane & 15;
    const int g = lane >> 4;
    const int r0 = by * 128, c0 = bx * 128;
    const int sr = t >> 3;
    const int sc = t & 7;

    f32x4 acc[4][4];
#pragma unroll
    for (int i = 0; i < 4; ++i)
#pragma unroll
        for (int j = 0; j < 4; ++j) acc[i][j] = (f32x4){0.f, 0.f, 0.f, 0.f};

    for (int kt = 0; kt < (K >> 6); ++kt) {
        const int kb = kt * 64;
        __syncthreads();
#pragma unroll
        for (int pp = 0; pp < 4; ++pp) {
            const int r = pp * 32 + sr;
            uint4 va = *(const uint4*)(N16 + (size_t)(r0 + r) * K + kb + sc * 8);
            uint4 vb = *(const uint4*)(N16 + (size_t)(c0 + r) * K + kb + sc * 8);
            const int d = r * 64 + ((((sc * 16) ^ ((r & 7) << 4))) >> 1);
            *(uint4*)&As[d] = va;
            *(uint4*)&Bs[d] = vb;
        }
        __syncthreads();
#pragma unroll
        for (int ks = 0; ks < 2; ++ks) {
            const int ko = ((ks * 64 + g * 16) ^ ((fr & 7) << 4)) >> 1;
            f16x8 af[4], bf[4];
#pragma unroll
            for (int i = 0; i < 4; ++i) {
                af[i] = *(const f16x8*)&As[(wr * 64 + i * 16 + fr) * 64 + ko];
                bf[i] = *(const f16x8*)&Bs[(wc * 64 + i * 16 + fr) * 64 + ko];
            }
#pragma unroll
            for (int i = 0; i < 4; ++i)
#pragma unroll
                for (int j = 0; j < 4; ++j)
                    acc[i][j] = __builtin_amdgcn_mfma_f32_16x16x32_f16(af[i], bf[j], acc[i][j], 0, 0, 0);
        }
    }
    __syncthreads();

    float lsum = 0.f;
    const int r4 = g * 4;
#pragma unroll
    for (int i = 0; i < 4; ++i) {
#pragma unroll
        for (int q = 0; q < 4; ++q) {
            const int lr = wr * 64 + i * 16 + r4 + q;
            const int row = r0 + lr;
#pragma unroll
            for (int j = 0; j < 4; ++j) {
                const int lc2 = wc * 64 + j * 16 + fr;
                const int col = c0 + lc2;
                float v = fminf(fmaxf(acc[i][j][q], 0.f), 1.f);
                if (row == col) v = 0.f;
                lsum += v;
                *(__half*)(Cb + lr * 256 + ((lc2 * 2) ^ ((lr & 7) << 4))) = __float2half(v);
            }
        }
    }
    __syncthreads();

#pragma unroll
    for (int pp = 0; pp < 4; ++pp) {
        const int rbl2 = pp * 4 + (t >> 6);
        const int rbl = rbl2 >> 1, ks2l = rbl2 & 1;
        const int l = t & 63;
        const int lr = rbl * 16 + (l & 15);
        const int e0 = ks2l * 64 + (l >> 4) * 8;
        uint4 v0 = *(const uint4*)(Cb + lr * 256 + ((e0 * 2) ^ ((lr & 7) << 4)));
        uint4 v1 = *(const uint4*)(Cb + lr * 256 + (((e0 + 32) * 2) ^ ((lr & 7) << 4)));
        const size_t rb = (size_t)(by * 8 + rbl);
        const size_t ks2 = (size_t)(bx * 2 + ks2l);
        char* dst = (char*)A16f + (size_t)lp * 33554432 + rb * 131072 + ks2 * 2048 + l * 32;
        *(uint4*)dst = v0;
        *(uint4*)(dst + 16) = v1;
    }

    for (int off = 32; off > 0; off >>= 1) lsum += __shfl_down(lsum, off, 64);
    if (lane == 0) reds[wave] = lsum;
    __syncthreads();
    if (t == 0) partials[lp * 1024 + blk] = reds[0] + reds[1] + reds[2] + reds[3];
}

// ---------------------------------------------------------------------------
// mean per problem: block lp reduces partials[lp][0..1023] -> scal[lp]
// ---------------------------------------------------------------------------
__global__ __launch_bounds__(256) void mean_all_kernel(const float* __restrict__ partials,
                                                       float* __restrict__ scal)
{
    __shared__ float red[4];
    const int t = threadIdx.x, lp = blockIdx.x;
    float s = 0.f;
    for (int i = t; i < 1024; i += 256) s += partials[lp * 1024 + i];
    for (int off = 32; off > 0; off >>= 1) s += __shfl_down(s, off, 64);
    if ((t & 63) == 0) red[t >> 6] = s;
    __syncthreads();
    if (t == 0) scal[lp] = (red[0] + red[1] + red[2] + red[3]) * (1.0f / 16777216.0f);
}

// ---------------------------------------------------------------------------
// Quantize to 4-bit codes round(16*(a<mean?0:a)), linear frag order.
// Grid pcount*4096; lp = blk>>12.
// ---------------------------------------------------------------------------
__global__ __launch_bounds__(256) void abar4_all_kernel(const __half* __restrict__ A16f,
                                                        uchar* __restrict__ A4,
                                                        const float* __restrict__ scal)
{
    const int lp = blockIdx.x >> 12;
    const float mean = scal[lp];
    const size_t i = (size_t)(blockIdx.x & 4095) * 256 + threadIdx.x;
    const __half* src = A16f + (size_t)lp * 16777216 + i * 16;
    uint4 u0 = *(const uint4*)(src);
    uint4 u1 = *(const uint4*)(src + 8);
    __half h[16];
    *(uint4*)h = u0;
    *(uint4*)(h + 8) = u1;
    unsigned d0 = 0, d1 = 0;
#pragma unroll
    for (int k = 0; k < 8; ++k) {
        float a = __half2float(h[k]);
        float v = (a < mean) ? 0.f : a;
        unsigned n = (unsigned)fminf(v * 16.f + 0.5f, 15.f);
        d0 |= n << (4 * k);
    }
#pragma unroll
    for (int k = 0; k < 8; ++k) {
        float a = __half2float(h[8 + k]);
        float v = (a < mean) ? 0.f : a;
        unsigned n = (unsigned)fminf(v * 16.f + 0.5f, 15.f);
        d1 |= n << (4 * k);
    }
    uint2 o; o.x = d0; o.y = d1;
    *(uint2*)(A4 + (size_t)lp * 8388608 + i * 8) = o;
}

// ---------------------------------------------------------------------------
// X0 init + Scol init (blocks 0..30) + label histogram (block 0)
// ---------------------------------------------------------------------------
__global__ __launch_bounds__(256) void init_kernel(const int* __restrict__ labels,
                                                   uchar* __restrict__ X8_0,
                                                   uchar* __restrict__ X8_1,
                                                   float* __restrict__ X32,
                                                   float* __restrict__ Scol)
{
    __shared__ int hist[16];
    const int blk = blockIdx.x;
    const int t = threadIdx.x;
    const int idx = blk * 256 + t;   // 5*16*4096 = 327680
    const int p = idx >> 16;
    const int rem = idx & 65535;
    const int c = rem >> 12, j = rem & 4095;
    float v;
    if (c >= 10) v = 0.f;
    else if (j < 2048) v = (labels[j] == c) ? 1.0f : 0.0f;
    else v = 0.1f;
    unsigned pk = __builtin_amdgcn_cvt_pk_fp8_f32(v, v, 0, false);
    X8_0[(size_t)p * 65536 + xfrag_off(c, j)] = (uchar)(pk & 0xff);
    if (c >= 10) X8_1[(size_t)p * 65536 + xfrag_off(c, j)] = 0;
    if (c < 10) X32[((size_t)p * 4096 + j) * 10 + c] = v;

    if (blk == 0) {
        if (t < 16) hist[t] = 0;
        __syncthreads();
        for (int i = t; i < 2048; i += 256) atomicAdd(&hist[labels[i]], 1);
        __syncthreads();
        if (t < 80) {
            const int pp = t >> 4, cc = t & 15;
            Scol[pp * 16 + cc] = (cc < 10) ? ((float)hist[cc] + 204.8f) : 0.f;
        }
    } else if (blk <= 30) {
        if (t < 80) Scol[blk * 80 + t] = 0.f;
    }
}

// ---------------------------------------------------------------------------
// Pack w1 (300x150) and w2 (150x75) into fragment-major fp16 B-operand form.
// ---------------------------------------------------------------------------
__global__ __launch_bounds__(256) void wfrag_kernel(const float* __restrict__ w1,
                                                    const float* __restrict__ w2,
                                                    __half* __restrict__ W1f,
                                                    __half* __restrict__ W2f)
{
    int idx = blockIdx.x * 256 + threadIdx.x;   // 51200 + 12800 = 64000
    if (idx < 51200) {
        const int frag = idx >> 9, e9 = idx & 511;
        const int s = frag / 10, j = frag % 10;
        const int g = e9 >> 7, fr = (e9 >> 3) & 15, e = e9 & 7;
        const int k = s * 32 + g * 8 + e, n = j * 16 + fr;
        const float v = (k < 300 && n < 150) ? w1[(size_t)k * 150 + n] : 0.f;
        W1f[idx] = __float2half(v);
    } else if (idx < 64000) {
        const int i2 = idx - 51200;
        const int frag = i2 >> 9, e9 = i2 & 511;
        const int s = frag / 5, j = frag % 5;
        const int g = e9 >> 7, fr = (e9 >> 3) & 15, e = e9 & 7;
        const int k = s * 32 + g * 8 + e, n = j * 16 + fr;
        const float v = (k < 150 && n < 75) ? w2[(size_t)k * 75 + n] : 0.f;
        W2f[i2] = __float2half(v);
    }
}

// ---------------------------------------------------------------------------
// One GTG iteration: 4-bit A expanded in-register to fp8 (LUT), fp8 MFMA.
// 5 blocks/CU residency (min 5 waves/EU).
// ---------------------------------------------------------------------------
__global__ __launch_bounds__(256, 5) void gtg8_kernel(
    const uchar* __restrict__ A4f,
    const uchar* __restrict__ X8i, uchar* __restrict__ X8o,
    const float* __restrict__ X32i, float* __restrict__ X32o,
    __half* __restrict__ Xs16f, float* __restrict__ ytacc,
    float* __restrict__ Scol, int it, int pbase)
{
    __shared__ float yred[4][256];
    const int t = threadIdx.x;
    const int lane = t & 63, wave = t >> 6;
    const int p = pbase + (blockIdx.x >> 8);
    const int pl = p - pbase;
    const int rb = blockIdx.x & 255;

    const uchar* Ab = A4f + (size_t)pl * 8388608 + (size_t)rb * 32768
                    + wave * 8192 + lane * 8;
    const uchar* Xb = X8i + (size_t)p * 65536 + wave * 16384 + lane * 16;

    f32x4 acc0 = {0.f, 0.f, 0.f, 0.f};
    f32x4 acc1 = {0.f, 0.f, 0.f, 0.f};
#pragma unroll
    for (int u = 0; u < 16; ++u) {
        uint2 a4 = *(const uint2*)(Ab + u * 512);
        uint4 bv = *(const uint4*)(Xb + u * 1024);
        unsigned e00, e01, e10, e11;
        expand4(a4.x, e00, e01);
        expand4(a4.y, e10, e11);
        acc0 = __builtin_amdgcn_mfma_f32_16x16x32_fp8_fp8(
            mk64(e00, e01), mk64(bv.x, bv.y), acc0, 0, 0, 0);
        acc1 = __builtin_amdgcn_mfma_f32_16x16x32_fp8_fp8(
            mk64(e10, e11), mk64(bv.z, bv.w), acc1, 0, 0, 0);
    }
    {
        const int r4 = (lane >> 4) * 4;
        const int fr = lane & 15;
#pragma unroll
        for (int q = 0; q < 4; ++q)
            yred[wave][(r4 + q) * 16 + fr] = acc0[q] + acc1[q];
    }
    __syncthreads();

    // ---- update phase: thread t -> row r=t>>4, class c=t&15
    const int r = t >> 4, c = t & 15;
    const int row = rb * 16 + r;
    const float T = yred[0][t] + yred[1][t] + yred[2][t] + yred[3][t];
    const float y = Scol[it * 80 + pl * 16 + c] - T;
    const float x = (c < 10) ? X32i[((size_t)p * 4096 + row) * 10 + c] : 0.f;
    const float m = x * y;
    float s = m;
    s += __shfl_xor(s, 1, 16);
    s += __shfl_xor(s, 2, 16);
    s += __shfl_xor(s, 4, 16);
    s += __shfl_xor(s, 8, 16);
    const float dv = m / (s + 1e-8f);
    const float xn = x + dv;
    if (c < 10) {
        X32o[((size_t)p * 4096 + row) * 10 + c] = xn;
        unsigned pk = __builtin_amdgcn_cvt_pk_fp8_f32(xn, xn, 0, false);
        X8o[(size_t)p * 65536 + xfrag_off(c, row)] = (uchar)(pk & 0xff);
        if (p < 4) {
            const int k = c * 30 + it;
            Xs16f[(size_t)p * 1310720 + xsfrag_off(row, k)] = __float2half(xn);
        }
    }
    if (p == 4) {
        float e = (c < 10) ? (-dv * logf(dv + 1e-8f)) : 0.f;
        e += __shfl_xor(e, 1, 16);
        e += __shfl_xor(e, 2, 16);
        e += __shfl_xor(e, 4, 16);
        e += __shfl_xor(e, 8, 16);
        if (c == 0) {
            float prev = (it == 0) ? 0.f : ytacc[row];
            ytacc[row] = prev + e;
        }
    }

    // ---- colsum for next iteration
    __syncthreads();
    yred[0][t] = (c < 10) ? xn : 0.f;
    __syncthreads();
    if (t < 10) {
        float sc = 0.f;
#pragma unroll
        for (int rr = 0; rr < 16; ++rr) sc += yred[0][t + rr * 16];
        atomicAdd(&Scol[(it + 1) * 80 + pl * 16 + t], sc);
    }
}

// ---------------------------------------------------------------------------
// MFMA MLP (layers 1+2, all levels). 256 blocks x 4 waves.
// ---------------------------------------------------------------------------
__global__ __launch_bounds__(256) void mlp_mfma_kernel(const __half* __restrict__ Xs16f,
                                                       const __half* __restrict__ W1f,
                                                       const __half* __restrict__ W2f,
                                                       const float* __restrict__ b1,
                                                       const float* __restrict__ b2,
                                                       float* __restrict__ H2)
{
    __shared__ char h1s[4][16 * 384];
    __shared__ float b1s[160];
    __shared__ float b2s[80];
    const int t = threadIdx.x;
    const int lane = t & 63, wave = t >> 6;
    const int fr = lane & 15, g = lane >> 4;
    const int lvl = blockIdx.x >> 6;
    const int rb = (blockIdx.x & 63) * 4 + wave;

    if (t < 160) b1s[t] = (t < 150) ? b1[t] : 0.f;
    else if (t < 240) b2s[t - 160] = (t < 235) ? b2[t - 160] : 0.f;
    __syncthreads();

    const __half* Abase = Xs16f + (size_t)lvl * 1310720 + (size_t)rb * 5120;
    f32x4 acc1[10];
#pragma unroll
    for (int j = 0; j < 10; ++j) acc1[j] = (f32x4){0.f, 0.f, 0.f, 0.f};
#pragma unroll
    for (int s = 0; s < 10; ++s) {
        f16x8 a = *(const f16x8*)(Abase + s * 512 + lane * 8);
#pragma unroll
        for (int j = 0; j < 10; ++j) {
            f16x8 b = *(const f16x8*)(W1f + (s * 10 + j) * 512 + lane * 8);
            acc1[j] = __builtin_amdgcn_mfma_f32_16x16x32_f16(a, b, acc1[j], 0, 0, 0);
        }
    }
    char* hw = h1s[wave];
#pragma unroll
    for (int j = 0; j < 10; ++j) {
#pragma unroll
        for (int q = 0; q < 4; ++q) {
            const int row = g * 4 + q;
            const int col = j * 16 + fr;
            float v = fmaxf(acc1[j][q] + b1s[col], 0.f);
            *(__half*)(hw + row * 384 + ((col * 2) ^ ((row & 7) << 4))) = __float2half(v);
        }
    }
    __syncthreads();

    f32x4 acc2[5];
#pragma unroll
    for (int j = 0; j < 5; ++j) acc2[j] = (f32x4){0.f, 0.f, 0.f, 0.f};
#pragma unroll
    for (int s = 0; s < 5; ++s) {
        f16x8 a = *(const f16x8*)(hw + fr * 384 + ((s * 64 + g * 16) ^ ((fr & 7) << 4)));
#pragma unroll
        for (int j = 0; j < 5; ++j) {
            f16x8 b = *(const f16x8*)(W2f + (s * 5 + j) * 512 + lane * 8);
            acc2[j] = __builtin_amdgcn_mfma_f32_16x16x32_f16(a, b, acc2[j], 0, 0, 0);
        }
    }
#pragma unroll
    for (int j = 0; j < 5; ++j) {
        const int col = j * 16 + fr;
        if (col < 75) {
#pragma unroll
            for (int q = 0; q < 4; ++q) {
                const int row = rb * 16 + g * 4 + q;
                float v = fmaxf(acc2[j][q] + b2s[col], 0.f);
                H2[(size_t)row * 300 + lvl * 75 + col] = v;
            }
        }
    }
}

// ---------------------------------------------------------------------------
// Final: y_pred = H2 @ w3 + b3; y_true = ytacc/30; labelled_mask
// ---------------------------------------------------------------------------
__global__ __launch_bounds__(256) void final_kernel(const float* __restrict__ H2,
                                                    const float* __restrict__ w3,
                                                    const float* __restrict__ b3,
                                                    const float* __restrict__ ytacc,
                                                    float* __restrict__ out)
{
    __shared__ float w[300];
    const int t = threadIdx.x;
    const int b = blockIdx.x * 256 + t;
    for (int i = t; i < 300; i += 256) w[i] = w3[i];
    __syncthreads();
    float acc = b3[0];
    const float4* row = (const float4*)(H2 + (size_t)b * 300);
    for (int k4 = 0; k4 < 75; ++k4) {
        float4 v = row[k4];
        acc += v.x * w[k4 * 4] + v.y * w[k4 * 4 + 1] + v.z * w[k4 * 4 + 2] + v.w * w[k4 * 4 + 3];
    }
    out[b] = acc;
    out[4096 + b] = ytacc[b] * (1.0f / 30.0f);
    out[2 * 4096 + b] = (b < 2048) ? 1.0f : 0.0f;
}

// ---------------------------------------------------------------------------
extern "C" void kernel_launch(void* const* d_in, const int* in_sizes, int n_in,
                              void* d_out, int out_size, void* d_ws, size_t ws_size,
                              hipStream_t stream)
{
    (void)in_sizes; (void)n_in; (void)out_size;

    const float* feats[4] = {(const float*)d_in[0], (const float*)d_in[1],
                             (const float*)d_in[2], (const float*)d_in[3]};
    const float* embedds = (const float*)d_in[4];
    const int* labels = (const int*)d_in[6];
    const float* lsw[4] = {(const float*)d_in[7], (const float*)d_in[9],
                           (const float*)d_in[11], (const float*)d_in[13]};
    const float* lsb[4] = {(const float*)d_in[8], (const float*)d_in[10],
                           (const float*)d_in[12], (const float*)d_in[14]};
    const float* w1 = (const float*)d_in[15];
    const float* b1 = (const float*)d_in[16];
    const float* w2 = (const float*)d_in[17];
    const float* b2 = (const float*)d_in[18];
    const float* w3 = (const float*)d_in[19];
    const float* b3 = (const float*)d_in[20];

    // fused: 5 A4 slices (40MB) + 5 A16f slices (160MB); else 1+1
    const bool fused = ws_size >= 256000000ULL;
    const size_t A4_BYTES  = fused ? 41943040ULL : 8388608ULL;
    const size_t A16_BYTES = fused ? 167772160ULL : 33554432ULL;

    char* ws = (char*)d_ws;
    uchar* A4       = (uchar*)(ws);
    __half* A16f    = (__half*)(ws + A4_BYTES);
    char* base      = ws + A4_BYTES + A16_BYTES;
    __half* N16all  = (__half*)(base);                //  8388608
    uchar* Xt8      = (uchar*)(base + 8388608);       //  2 x 327680
    float* X32      = (float*)(base + 9043968);       //  2 x 819200
    __half* Xs16f   = (__half*)(base + 10682368);     //  10485760
    float* H2       = (float*)(base + 21168128);      //  4915200
    float* ytacc    = (float*)(base + 26083328);      //  16384
    float* partials = (float*)(base + 26099712);      //  20480
    float* scal     = (float*)(base + 26120192);      //  256
    float* Scol     = (float*)(base + 26120448);      //  16384
    __half* W1f     = (__half*)(base + 26136832);     //  102400
    __half* W2f     = (__half*)(base + 26239232);     //  25600
    float* pooled   = (float*)(base + 26264832);      //  15728640

    uchar* Xt8b[2] = {Xt8, Xt8 + 327680};
    float* X32b[2] = {X32, X32 + 204800};
    float* out = (float*)d_out;

    auto run_iters = [&](const uchar* Ab4, int pbase, int nprob) {
        init_kernel<<<1280, 256, 0, stream>>>(labels, Xt8b[0], Xt8b[1], X32b[0], Scol);
        for (int it = 0; it < 30; ++it) {
            const int i = it & 1, o = i ^ 1;
            gtg8_kernel<<<nprob * 256, 256, 0, stream>>>(
                Ab4, Xt8b[i], Xt8b[o], X32b[i], X32b[o], Xs16f, ytacc, Scol, it, pbase);
        }
    };

    wfrag_kernel<<<250, 256, 0, stream>>>(w1, w2, W1f, W2f);
    hipMemsetAsync(Xs16f, 0, 10485760, stream);

    // ---- prep: pooled -> N16all (all problems)
    pool_all_kernel<<<16384, 256, 0, stream>>>(feats[0], feats[1], feats[2], feats[3], pooled);
    lsn_all_kernel<<<16384, 128, 0, stream>>>(pooled,
        lsw[0], lsb[0], lsw[1], lsb[1], lsw[2], lsb[2], lsw[3], lsb[3], N16all);
    norm512_kernel<<<4096, 256, 0, stream>>>(embedds, N16all);

    if (fused) {
        a_gemm_all<<<5 * 1024, 256, 0, stream>>>(N16all, A16f, partials, 0);
        mean_all_kernel<<<5, 256, 0, stream>>>(partials, scal);
        abar4_all_kernel<<<5 * 4096, 256, 0, stream>>>(A16f, A4, scal);
        run_iters(A4, 0, 5);
    } else {
        for (int p = 0; p < 5; ++p) {
            a_gemm_all<<<1024, 256, 0, stream>>>(N16all, A16f, partials, p);
            mean_all_kernel<<<1, 256, 0, stream>>>(partials, scal);
            abar4_all_kernel<<<4096, 256, 0, stream>>>(A16f, A4, scal);
            run_iters(A4, p, 1);
        }
    }

    mlp_mfma_kernel<<<256, 256, 0, stream>>>(Xs16f, W1f, W2f, b1, b2, H2);
    final_kernel<<<16, 256, 0, stream>>>(H2, w3, b3, ytacc, out);
}

// Round 16
// 786.886 us; speedup vs baseline: 1.0062x; 1.0038x over previous
//
#include <hip/hip_runtime.h>
#include <hip/hip_fp16.h>

typedef _Float16 f16x8 __attribute__((ext_vector_type(8)));
typedef float f32x4 __attribute__((ext_vector_type(4)));
typedef unsigned char uchar;

static __device__ __forceinline__ long long mk64(unsigned lo, unsigned hi)
{
    return (long long)(((unsigned long long)hi << 32) | (unsigned long long)lo);
}

// fragment-layout offset for X8 (B-operand): class c, row j
static __device__ __forceinline__ int xfrag_off(int c, int j)
{
    return (j >> 6) * 1024 + (((j >> 3) & 3) * 16 + c) * 16 + ((j >> 5) & 1) * 8 + (j & 7);
}

// fragment-layout offset (halves) for Xs16f (A-operand): row (0..4095), k (0..319)
static __device__ __forceinline__ int xsfrag_off(int row, int k)
{
    return (row >> 4) * 5120 + (k >> 5) * 512 + (((k >> 3) & 3) * 16 + (row & 15)) * 8 + (k & 7);
}

// nibble codes -> fp8 e4m3 bytes of k/16 (exact): LUT via v_perm
#define T03 0x24201800u
#define T47 0x2E2C2A28u
#define T8B 0x33323130u
#define TCF 0x37363534u

static __device__ __forceinline__ void expand4(unsigned w, unsigned& o0, unsigned& o1)
{
    unsigned even = w & 0x0F0F0F0Fu;
    unsigned odd  = (w >> 4) & 0x0F0F0F0Fu;
    unsigned i_lo = __builtin_amdgcn_perm(odd, even, 0x05010400u);
    unsigned i_hi = __builtin_amdgcn_perm(odd, even, 0x07030602u);
    {
        unsigned i3 = i_lo & 0x07070707u;
        unsigned ta = __builtin_amdgcn_perm(T47, T03, i3);
        unsigned tb = __builtin_amdgcn_perm(TCF, T8B, i3);
        unsigned m  = ((i_lo >> 3) & 0x01010101u) * 0xFFu;
        o0 = ta ^ ((ta ^ tb) & m);
    }
    {
        unsigned i3 = i_hi & 0x07070707u;
        unsigned ta = __builtin_amdgcn_perm(T47, T03, i3);
        unsigned tb = __builtin_amdgcn_perm(TCF, T8B, i3);
        unsigned m  = ((i_hi >> 3) & 0x01010101u) * 0xFFu;
        o1 = ta ^ ((ta ^ tb) & m);
    }
}

// ---------------------------------------------------------------------------
// COALESCED pool with FORCED-batched loads: sched_barrier(0) pins all NITER
// global loads before any reduction instruction, so the compiler cannot
// re-fuse load+reduce (which collapsed memory-level parallelism to 1).
// Block = one (level,row).
// ---------------------------------------------------------------------------
template <int NITER, int S2>
static __device__ __forceinline__ void pool_row(const float4* __restrict__ src,
                                                float* __restrict__ dst, int t)
{
    float4 v[NITER];
#pragma unroll
    for (int i = 0; i < NITER; ++i) v[i] = src[i * 256 + t];
    __builtin_amdgcn_sched_barrier(0);   // all loads issued before any use
#pragma unroll
    for (int i = 0; i < NITER; ++i) {
        float s = v[i].x + v[i].y + v[i].z + v[i].w;
        if (S2 == 64) {
            s += __shfl_xor(s, 1, 16);
            s += __shfl_xor(s, 2, 16);
            s += __shfl_xor(s, 4, 16);
            s += __shfl_xor(s, 8, 16);
            if ((t & 15) == 0) dst[i * 16 + (t >> 4)] = s * (1.0f / 64.f);
        } else {
            s += __shfl_xor(s, 1, 4);
            s += __shfl_xor(s, 2, 4);
            if ((t & 3) == 0) dst[i * 64 + (t >> 2)] = s * (1.0f / 16.f);
        }
    }
}

__global__ __launch_bounds__(256) void pool_all_kernel(
    const float* __restrict__ f0, const float* __restrict__ f1,
    const float* __restrict__ f2, const float* __restrict__ f3,
    float* __restrict__ pooled)
{
    const int b = blockIdx.x;               // 16384 = 4 levels x 4096 rows
    const int p = b >> 12, row = b & 4095;
    const int t = threadIdx.x;
    switch (p) {
        case 0:
            pool_row<4, 64>((const float4*)(f0 + (size_t)row * 4096),
                            pooled + (size_t)row * 64, t);
            break;
        case 1:
            pool_row<8, 64>((const float4*)(f1 + (size_t)row * 8192),
                            pooled + 262144 + (size_t)row * 128, t);
            break;
        case 2:
            pool_row<4, 16>((const float4*)(f2 + (size_t)row * 4096),
                            pooled + 786432 + (size_t)row * 256, t);
            break;
        default:
            pool_row<8, 16>((const float4*)(f3 + (size_t)row * 8192),
                            pooled + 1835008 + (size_t)row * 512, t);
            break;
    }
}

// ---------------------------------------------------------------------------
// Linear+ReLU+row-normalize for all 4 levels in one dispatch.
// Grid 16384 blocks x 128 threads; p = blk>>12, row = blk&4095.
// ---------------------------------------------------------------------------
__global__ __launch_bounds__(128) void lsn_all_kernel(
    const float* __restrict__ pooled,
    const float* __restrict__ lw0, const float* __restrict__ lb0,
    const float* __restrict__ lw1, const float* __restrict__ lb1,
    const float* __restrict__ lw2, const float* __restrict__ lb2,
    const float* __restrict__ lw3, const float* __restrict__ lb3,
    __half* __restrict__ N16all)
{
    __shared__ float pl[512];
    __shared__ float red2[2];
    const int t = threadIdx.x;
    const int p = blockIdx.x >> 12;
    const int row = blockIdx.x & 4095;
    const float* w; const float* b; int C, pOff;
    switch (p) {
        case 0:  w = lw0; b = lb0; C = 64;  pOff = 0;       break;
        case 1:  w = lw1; b = lb1; C = 128; pOff = 262144;  break;
        case 2:  w = lw2; b = lb2; C = 256; pOff = 786432;  break;
        default: w = lw3; b = lb3; C = 512; pOff = 1835008; break;
    }
    for (int k = t; k < C; k += 128) pl[k] = pooled[pOff + (size_t)row * C + k];
    __syncthreads();
    float acc = b[t];
    for (int k = 0; k < C; ++k) acc = fmaf(pl[k], w[(size_t)k * 128 + t], acc);
    float v = fmaxf(acc, 0.f);
    float ss = v * v;
    for (int off = 32; off > 0; off >>= 1) ss += __shfl_down(ss, off, 64);
    if ((t & 63) == 0) red2[t >> 6] = ss;
    __syncthreads();
    float inv = 1.0f / fmaxf(sqrtf(red2[0] + red2[1]), 1e-12f);
    N16all[(size_t)p * 524288 + (size_t)row * 128 + t] = __float2half(v * inv);
}

// ---------------------------------------------------------------------------
// Normalize embedds rows (d=512) -> N16all + 2097152
// ---------------------------------------------------------------------------
__global__ __launch_bounds__(256) void norm512_kernel(const float* __restrict__ E,
                                                      __half* __restrict__ N16all)
{
    __shared__ float red4[4];
    const int b = blockIdx.x, t = threadIdx.x;
    float2 v = *(const float2*)(E + (size_t)b * 512 + t * 2);
    float ss = v.x * v.x + v.y * v.y;
    for (int off = 32; off > 0; off >>= 1) ss += __shfl_down(ss, off, 64);
    if ((t & 63) == 0) red4[t >> 6] = ss;
    __syncthreads();
    float inv = 1.0f / fmaxf(sqrtf(red4[0] + red4[1] + red4[2] + red4[3]), 1e-12f);
    __half2 o;
    o.x = __float2half(v.x * inv);
    o.y = __float2half(v.y * inv);
    *(__half2*)(N16all + 2097152 + (size_t)b * 512 + t * 2) = o;
}

// ---------------------------------------------------------------------------
// All-problem MFMA GEMM. Grid pcount*1024; p = pbase + blk>>10, runtime K.
// ---------------------------------------------------------------------------
__global__ __launch_bounds__(256) void a_gemm_all(const __half* __restrict__ N16all,
                                                  __half* __restrict__ A16f,
                                                  float* __restrict__ partials,
                                                  int pbase)
{
    __shared__ __half smem[16384];   // As(8192) | Bs(8192); reused as Cst
    __shared__ float reds[4];
    __half* As = smem;
    __half* Bs = smem + 8192;
    char* Cb = (char*)smem;
    const int t = threadIdx.x;
    const int lane = t & 63, wave = t >> 6;
    const int lp = blockIdx.x >> 10;
    const int p = pbase + lp;
    const int blk = blockIdx.x & 1023;
    const int K = (p == 4) ? 512 : 128;
    const __half* N16 = N16all + ((p == 4) ? 2097152u : (unsigned)p * 524288u);
    const int bx = blk & 31, by = blk >> 5;
    const int wr = wave >> 1, wc = wave & 1;
    const int fr = lane & 15;
    const int g = lane >> 4;
    const int r0 = by * 128, c0 = bx * 128;
    const int sr = t >> 3;
    const int sc = t & 7;

    f32x4 acc[4][4];
#pragma unroll
    for (int i = 0; i < 4; ++i)
#pragma unroll
        for (int j = 0; j < 4; ++j) acc[i][j] = (f32x4){0.f, 0.f, 0.f, 0.f};

    for (int kt = 0; kt < (K >> 6); ++kt) {
        const int kb = kt * 64;
        __syncthreads();
#pragma unroll
        for (int pp = 0; pp < 4; ++pp) {
            const int r = pp * 32 + sr;
            uint4 va = *(const uint4*)(N16 + (size_t)(r0 + r) * K + kb + sc * 8);
            uint4 vb = *(const uint4*)(N16 + (size_t)(c0 + r) * K + kb + sc * 8);
            const int d = r * 64 + ((((sc * 16) ^ ((r & 7) << 4))) >> 1);
            *(uint4*)&As[d] = va;
            *(uint4*)&Bs[d] = vb;
        }
        __syncthreads();
#pragma unroll
        for (int ks = 0; ks < 2; ++ks) {
            const int ko = ((ks * 64 + g * 16) ^ ((fr & 7) << 4)) >> 1;
            f16x8 af[4], bf[4];
#pragma unroll
            for (int i = 0; i < 4; ++i) {
                af[i] = *(const f16x8*)&As[(wr * 64 + i * 16 + fr) * 64 + ko];
                bf[i] = *(const f16x8*)&Bs[(wc * 64 + i * 16 + fr) * 64 + ko];
            }
#pragma unroll
            for (int i = 0; i < 4; ++i)
#pragma unroll
                for (int j = 0; j < 4; ++j)
                    acc[i][j] = __builtin_amdgcn_mfma_f32_16x16x32_f16(af[i], bf[j], acc[i][j], 0, 0, 0);
        }
    }
    __syncthreads();

    float lsum = 0.f;
    const int r4 = g * 4;
#pragma unroll
    for (int i = 0; i < 4; ++i) {
#pragma unroll
        for (int q = 0; q < 4; ++q) {
            const int lr = wr * 64 + i * 16 + r4 + q;
            const int row = r0 + lr;
#pragma unroll
            for (int j = 0; j < 4; ++j) {
                const int lc2 = wc * 64 + j * 16 + fr;
                const int col = c0 + lc2;
                float v = fminf(fmaxf(acc[i][j][q], 0.f), 1.f);
                if (row == col) v = 0.f;
                lsum += v;
                *(__half*)(Cb + lr * 256 + ((lc2 * 2) ^ ((lr & 7) << 4))) = __float2half(v);
            }
        }
    }
    __syncthreads();

#pragma unroll
    for (int pp = 0; pp < 4; ++pp) {
        const int rbl2 = pp * 4 + (t >> 6);
        const int rbl = rbl2 >> 1, ks2l = rbl2 & 1;
        const int l = t & 63;
        const int lr = rbl * 16 + (l & 15);
        const int e0 = ks2l * 64 + (l >> 4) * 8;
        uint4 v0 = *(const uint4*)(Cb + lr * 256 + ((e0 * 2) ^ ((lr & 7) << 4)));
        uint4 v1 = *(const uint4*)(Cb + lr * 256 + (((e0 + 32) * 2) ^ ((lr & 7) << 4)));
        const size_t rb = (size_t)(by * 8 + rbl);
        const size_t ks2 = (size_t)(bx * 2 + ks2l);
        char* dst = (char*)A16f + (size_t)lp * 33554432 + rb * 131072 + ks2 * 2048 + l * 32;
        *(uint4*)dst = v0;
        *(uint4*)(dst + 16) = v1;
    }

    for (int off = 32; off > 0; off >>= 1) lsum += __shfl_down(lsum, off, 64);
    if (lane == 0) reds[wave] = lsum;
    __syncthreads();
    if (t == 0) partials[lp * 1024 + blk] = reds[0] + reds[1] + reds[2] + reds[3];
}

// ---------------------------------------------------------------------------
// mean per problem: block lp reduces partials[lp][0..1023] -> scal[lp]
// ---------------------------------------------------------------------------
__global__ __launch_bounds__(256) void mean_all_kernel(const float* __restrict__ partials,
                                                       float* __restrict__ scal)
{
    __shared__ float red[4];
    const int t = threadIdx.x, lp = blockIdx.x;
    float s = 0.f;
    for (int i = t; i < 1024; i += 256) s += partials[lp * 1024 + i];
    for (int off = 32; off > 0; off >>= 1) s += __shfl_down(s, off, 64);
    if ((t & 63) == 0) red[t >> 6] = s;
    __syncthreads();
    if (t == 0) scal[lp] = (red[0] + red[1] + red[2] + red[3]) * (1.0f / 16777216.0f);
}

// ---------------------------------------------------------------------------
// Quantize to 4-bit codes round(16*(a<mean?0:a)), linear frag order.
// Grid pcount*4096; lp = blk>>12.
// ---------------------------------------------------------------------------
__global__ __launch_bounds__(256) void abar4_all_kernel(const __half* __restrict__ A16f,
                                                        uchar* __restrict__ A4,
                                                        const float* __restrict__ scal)
{
    const int lp = blockIdx.x >> 12;
    const float mean = scal[lp];
    const size_t i = (size_t)(blockIdx.x & 4095) * 256 + threadIdx.x;
    const __half* src = A16f + (size_t)lp * 16777216 + i * 16;
    uint4 u0 = *(const uint4*)(src);
    uint4 u1 = *(const uint4*)(src + 8);
    __half h[16];
    *(uint4*)h = u0;
    *(uint4*)(h + 8) = u1;
    unsigned d0 = 0, d1 = 0;
#pragma unroll
    for (int k = 0; k < 8; ++k) {
        float a = __half2float(h[k]);
        float v = (a < mean) ? 0.f : a;
        unsigned n = (unsigned)fminf(v * 16.f + 0.5f, 15.f);
        d0 |= n << (4 * k);
    }
#pragma unroll
    for (int k = 0; k < 8; ++k) {
        float a = __half2float(h[8 + k]);
        float v = (a < mean) ? 0.f : a;
        unsigned n = (unsigned)fminf(v * 16.f + 0.5f, 15.f);
        d1 |= n << (4 * k);
    }
    uint2 o; o.x = d0; o.y = d1;
    *(uint2*)(A4 + (size_t)lp * 8388608 + i * 8) = o;
}

// ---------------------------------------------------------------------------
// X0 init + Scol init (blocks 0..30) + label histogram (block 0)
// ---------------------------------------------------------------------------
__global__ __launch_bounds__(256) void init_kernel(const int* __restrict__ labels,
                                                   uchar* __restrict__ X8_0,
                                                   uchar* __restrict__ X8_1,
                                                   float* __restrict__ X32,
                                                   float* __restrict__ Scol)
{
    __shared__ int hist[16];
    const int blk = blockIdx.x;
    const int t = threadIdx.x;
    const int idx = blk * 256 + t;   // 5*16*4096 = 327680
    const int p = idx >> 16;
    const int rem = idx & 65535;
    const int c = rem >> 12, j = rem & 4095;
    float v;
    if (c >= 10) v = 0.f;
    else if (j < 2048) v = (labels[j] == c) ? 1.0f : 0.0f;
    else v = 0.1f;
    unsigned pk = __builtin_amdgcn_cvt_pk_fp8_f32(v, v, 0, false);
    X8_0[(size_t)p * 65536 + xfrag_off(c, j)] = (uchar)(pk & 0xff);
    if (c >= 10) X8_1[(size_t)p * 65536 + xfrag_off(c, j)] = 0;
    if (c < 10) X32[((size_t)p * 4096 + j) * 10 + c] = v;

    if (blk == 0) {
        if (t < 16) hist[t] = 0;
        __syncthreads();
        for (int i = t; i < 2048; i += 256) atomicAdd(&hist[labels[i]], 1);
        __syncthreads();
        if (t < 80) {
            const int pp = t >> 4, cc = t & 15;
            Scol[pp * 16 + cc] = (cc < 10) ? ((float)hist[cc] + 204.8f) : 0.f;
        }
    } else if (blk <= 30) {
        if (t < 80) Scol[blk * 80 + t] = 0.f;
    }
}

// ---------------------------------------------------------------------------
// Pack w1 (300x150) and w2 (150x75) into fragment-major fp16 B-operand form.
// ---------------------------------------------------------------------------
__global__ __launch_bounds__(256) void wfrag_kernel(const float* __restrict__ w1,
                                                    const float* __restrict__ w2,
                                                    __half* __restrict__ W1f,
                                                    __half* __restrict__ W2f)
{
    int idx = blockIdx.x * 256 + threadIdx.x;   // 51200 + 12800 = 64000
    if (idx < 51200) {
        const int frag = idx >> 9, e9 = idx & 511;
        const int s = frag / 10, j = frag % 10;
        const int g = e9 >> 7, fr = (e9 >> 3) & 15, e = e9 & 7;
        const int k = s * 32 + g * 8 + e, n = j * 16 + fr;
        const float v = (k < 300 && n < 150) ? w1[(size_t)k * 150 + n] : 0.f;
        W1f[idx] = __float2half(v);
    } else if (idx < 64000) {
        const int i2 = idx - 51200;
        const int frag = i2 >> 9, e9 = i2 & 511;
        const int s = frag / 5, j = frag % 5;
        const int g = e9 >> 7, fr = (e9 >> 3) & 15, e = e9 & 7;
        const int k = s * 32 + g * 8 + e, n = j * 16 + fr;
        const float v = (k < 150 && n < 75) ? w2[(size_t)k * 75 + n] : 0.f;
        W2f[i2] = __float2half(v);
    }
}

// ---------------------------------------------------------------------------
// One GTG iteration: 4-bit A expanded in-register to fp8 (LUT), fp8 MFMA.
// 5 blocks/CU residency (min 5 waves/EU).
// ---------------------------------------------------------------------------
__global__ __launch_bounds__(256, 5) void gtg8_kernel(
    const uchar* __restrict__ A4f,
    const uchar* __restrict__ X8i, uchar* __restrict__ X8o,
    const float* __restrict__ X32i, float* __restrict__ X32o,
    __half* __restrict__ Xs16f, float* __restrict__ ytacc,
    float* __restrict__ Scol, int it, int pbase)
{
    __shared__ float yred[4][256];
    const int t = threadIdx.x;
    const int lane = t & 63, wave = t >> 6;
    const int p = pbase + (blockIdx.x >> 8);
    const int pl = p - pbase;
    const int rb = blockIdx.x & 255;

    const uchar* Ab = A4f + (size_t)pl * 8388608 + (size_t)rb * 32768
                    + wave * 8192 + lane * 8;
    const uchar* Xb = X8i + (size_t)p * 65536 + wave * 16384 + lane * 16;

    f32x4 acc0 = {0.f, 0.f, 0.f, 0.f};
    f32x4 acc1 = {0.f, 0.f, 0.f, 0.f};
#pragma unroll
    for (int u = 0; u < 16; ++u) {
        uint2 a4 = *(const uint2*)(Ab + u * 512);
        uint4 bv = *(const uint4*)(Xb + u * 1024);
        unsigned e00, e01, e10, e11;
        expand4(a4.x, e00, e01);
        expand4(a4.y, e10, e11);
        acc0 = __builtin_amdgcn_mfma_f32_16x16x32_fp8_fp8(
            mk64(e00, e01), mk64(bv.x, bv.y), acc0, 0, 0, 0);
        acc1 = __builtin_amdgcn_mfma_f32_16x16x32_fp8_fp8(
            mk64(e10, e11), mk64(bv.z, bv.w), acc1, 0, 0, 0);
    }
    {
        const int r4 = (lane >> 4) * 4;
        const int fr = lane & 15;
#pragma unroll
        for (int q = 0; q < 4; ++q)
            yred[wave][(r4 + q) * 16 + fr] = acc0[q] + acc1[q];
    }
    __syncthreads();

    // ---- update phase: thread t -> row r=t>>4, class c=t&15
    const int r = t >> 4, c = t & 15;
    const int row = rb * 16 + r;
    const float T = yred[0][t] + yred[1][t] + yred[2][t] + yred[3][t];
    const float y = Scol[it * 80 + pl * 16 + c] - T;
    const float x = (c < 10) ? X32i[((size_t)p * 4096 + row) * 10 + c] : 0.f;
    const float m = x * y;
    float s = m;
    s += __shfl_xor(s, 1, 16);
    s += __shfl_xor(s, 2, 16);
    s += __shfl_xor(s, 4, 16);
    s += __shfl_xor(s, 8, 16);
    const float dv = m / (s + 1e-8f);
    const float xn = x + dv;
    if (c < 10) {
        X32o[((size_t)p * 4096 + row) * 10 + c] = xn;
        unsigned pk = __builtin_amdgcn_cvt_pk_fp8_f32(xn, xn, 0, false);
        X8o[(size_t)p * 65536 + xfrag_off(c, row)] = (uchar)(pk & 0xff);
        if (p < 4) {
            const int k = c * 30 + it;
            Xs16f[(size_t)p * 1310720 + xsfrag_off(row, k)] = __float2half(xn);
        }
    }
    if (p == 4) {
        float e = (c < 10) ? (-dv * logf(dv + 1e-8f)) : 0.f;
        e += __shfl_xor(e, 1, 16);
        e += __shfl_xor(e, 2, 16);
        e += __shfl_xor(e, 4, 16);
        e += __shfl_xor(e, 8, 16);
        if (c == 0) {
            float prev = (it == 0) ? 0.f : ytacc[row];
            ytacc[row] = prev + e;
        }
    }

    // ---- colsum for next iteration
    __syncthreads();
    yred[0][t] = (c < 10) ? xn : 0.f;
    __syncthreads();
    if (t < 10) {
        float sc = 0.f;
#pragma unroll
        for (int rr = 0; rr < 16; ++rr) sc += yred[0][t + rr * 16];
        atomicAdd(&Scol[(it + 1) * 80 + pl * 16 + t], sc);
    }
}

// ---------------------------------------------------------------------------
// MFMA MLP (layers 1+2, all levels). 256 blocks x 4 waves.
// ---------------------------------------------------------------------------
__global__ __launch_bounds__(256) void mlp_mfma_kernel(const __half* __restrict__ Xs16f,
                                                       const __half* __restrict__ W1f,
                                                       const __half* __restrict__ W2f,
                                                       const float* __restrict__ b1,
                                                       const float* __restrict__ b2,
                                                       float* __restrict__ H2)
{
    __shared__ char h1s[4][16 * 384];
    __shared__ float b1s[160];
    __shared__ float b2s[80];
    const int t = threadIdx.x;
    const int lane = t & 63, wave = t >> 6;
    const int fr = lane & 15, g = lane >> 4;
    const int lvl = blockIdx.x >> 6;
    const int rb = (blockIdx.x & 63) * 4 + wave;

    if (t < 160) b1s[t] = (t < 150) ? b1[t] : 0.f;
    else if (t < 240) b2s[t - 160] = (t < 235) ? b2[t - 160] : 0.f;
    __syncthreads();

    const __half* Abase = Xs16f + (size_t)lvl * 1310720 + (size_t)rb * 5120;
    f32x4 acc1[10];
#pragma unroll
    for (int j = 0; j < 10; ++j) acc1[j] = (f32x4){0.f, 0.f, 0.f, 0.f};
#pragma unroll
    for (int s = 0; s < 10; ++s) {
        f16x8 a = *(const f16x8*)(Abase + s * 512 + lane * 8);
#pragma unroll
        for (int j = 0; j < 10; ++j) {
            f16x8 b = *(const f16x8*)(W1f + (s * 10 + j) * 512 + lane * 8);
            acc1[j] = __builtin_amdgcn_mfma_f32_16x16x32_f16(a, b, acc1[j], 0, 0, 0);
        }
    }
    char* hw = h1s[wave];
#pragma unroll
    for (int j = 0; j < 10; ++j) {
#pragma unroll
        for (int q = 0; q < 4; ++q) {
            const int row = g * 4 + q;
            const int col = j * 16 + fr;
            float v = fmaxf(acc1[j][q] + b1s[col], 0.f);
            *(__half*)(hw + row * 384 + ((col * 2) ^ ((row & 7) << 4))) = __float2half(v);
        }
    }
    __syncthreads();

    f32x4 acc2[5];
#pragma unroll
    for (int j = 0; j < 5; ++j) acc2[j] = (f32x4){0.f, 0.f, 0.f, 0.f};
#pragma unroll
    for (int s = 0; s < 5; ++s) {
        f16x8 a = *(const f16x8*)(hw + fr * 384 + ((s * 64 + g * 16) ^ ((fr & 7) << 4)));
#pragma unroll
        for (int j = 0; j < 5; ++j) {
            f16x8 b = *(const f16x8*)(W2f + (s * 5 + j) * 512 + lane * 8);
            acc2[j] = __builtin_amdgcn_mfma_f32_16x16x32_f16(a, b, acc2[j], 0, 0, 0);
        }
    }
#pragma unroll
    for (int j = 0; j < 5; ++j) {
        const int col = j * 16 + fr;
        if (col < 75) {
#pragma unroll
            for (int q = 0; q < 4; ++q) {
                const int row = rb * 16 + g * 4 + q;
                float v = fmaxf(acc2[j][q] + b2s[col], 0.f);
                H2[(size_t)row * 300 + lvl * 75 + col] = v;
            }
        }
    }
}

// ---------------------------------------------------------------------------
// Final: y_pred = H2 @ w3 + b3; y_true = ytacc/30; labelled_mask
// ---------------------------------------------------------------------------
__global__ __launch_bounds__(256) void final_kernel(const float* __restrict__ H2,
                                                    const float* __restrict__ w3,
                                                    const float* __restrict__ b3,
                                                    const float* __restrict__ ytacc,
                                                    float* __restrict__ out)
{
    __shared__ float w[300];
    const int t = threadIdx.x;
    const int b = blockIdx.x * 256 + t;
    for (int i = t; i < 300; i += 256) w[i] = w3[i];
    __syncthreads();
    float acc = b3[0];
    const float4* row = (const float4*)(H2 + (size_t)b * 300);
    for (int k4 = 0; k4 < 75; ++k4) {
        float4 v = row[k4];
        acc += v.x * w[k4 * 4] + v.y * w[k4 * 4 + 1] + v.z * w[k4 * 4 + 2] + v.w * w[k4 * 4 + 3];
    }
    out[b] = acc;
    out[4096 + b] = ytacc[b] * (1.0f / 30.0f);
    out[2 * 4096 + b] = (b < 2048) ? 1.0f : 0.0f;
}

// ---------------------------------------------------------------------------
extern "C" void kernel_launch(void* const* d_in, const int* in_sizes, int n_in,
                              void* d_out, int out_size, void* d_ws, size_t ws_size,
                              hipStream_t stream)
{
    (void)in_sizes; (void)n_in; (void)out_size;

    const float* feats[4] = {(const float*)d_in[0], (const float*)d_in[1],
                             (const float*)d_in[2], (const float*)d_in[3]};
    const float* embedds = (const float*)d_in[4];
    const int* labels = (const int*)d_in[6];
    const float* lsw[4] = {(const float*)d_in[7], (const float*)d_in[9],
                           (const float*)d_in[11], (const float*)d_in[13]};
    const float* lsb[4] = {(const float*)d_in[8], (const float*)d_in[10],
                           (const float*)d_in[12], (const float*)d_in[14]};
    const float* w1 = (const float*)d_in[15];
    const float* b1 = (const float*)d_in[16];
    const float* w2 = (const float*)d_in[17];
    const float* b2 = (const float*)d_in[18];
    const float* w3 = (const float*)d_in[19];
    const float* b3 = (const float*)d_in[20];

    // fused: 5 A4 slices (40MB) + 5 A16f slices (160MB); else 1+1
    const bool fused = ws_size >= 256000000ULL;
    const size_t A4_BYTES  = fused ? 41943040ULL : 8388608ULL;
    const size_t A16_BYTES = fused ? 167772160ULL : 33554432ULL;

    char* ws = (char*)d_ws;
    uchar* A4       = (uchar*)(ws);
    __half* A16f    = (__half*)(ws + A4_BYTES);
    char* base      = ws + A4_BYTES + A16_BYTES;
    __half* N16all  = (__half*)(base);                //  8388608
    uchar* Xt8      = (uchar*)(base + 8388608);       //  2 x 327680
    float* X32      = (float*)(base + 9043968);       //  2 x 819200
    __half* Xs16f   = (__half*)(base + 10682368);     //  10485760
    float* H2       = (float*)(base + 21168128);      //  4915200
    float* ytacc    = (float*)(base + 26083328);      //  16384
    float* partials = (float*)(base + 26099712);      //  20480
    float* scal     = (float*)(base + 26120192);      //  256
    float* Scol     = (float*)(base + 26120448);      //  16384
    __half* W1f     = (__half*)(base + 26136832);     //  102400
    __half* W2f     = (__half*)(base + 26239232);     //  25600
    float* pooled   = (float*)(base + 26264832);      //  15728640

    uchar* Xt8b[2] = {Xt8, Xt8 + 327680};
    float* X32b[2] = {X32, X32 + 204800};
    float* out = (float*)d_out;

    auto run_iters = [&](const uchar* Ab4, int pbase, int nprob) {
        init_kernel<<<1280, 256, 0, stream>>>(labels, Xt8b[0], Xt8b[1], X32b[0], Scol);
        for (int it = 0; it < 30; ++it) {
            const int i = it & 1, o = i ^ 1;
            gtg8_kernel<<<nprob * 256, 256, 0, stream>>>(
                Ab4, Xt8b[i], Xt8b[o], X32b[i], X32b[o], Xs16f, ytacc, Scol, it, pbase);
        }
    };

    wfrag_kernel<<<250, 256, 0, stream>>>(w1, w2, W1f, W2f);
    hipMemsetAsync(Xs16f, 0, 10485760, stream);

    // ---- prep: pooled -> N16all (all problems)
    pool_all_kernel<<<16384, 256, 0, stream>>>(feats[0], feats[1], feats[2], feats[3], pooled);
    lsn_all_kernel<<<16384, 128, 0, stream>>>(pooled,
        lsw[0], lsb[0], lsw[1], lsb[1], lsw[2], lsb[2], lsw[3], lsb[3], N16all);
    norm512_kernel<<<4096, 256, 0, stream>>>(embedds, N16all);

    if (fused) {
        a_gemm_all<<<5 * 1024, 256, 0, stream>>>(N16all, A16f, partials, 0);
        mean_all_kernel<<<5, 256, 0, stream>>>(partials, scal);
        abar4_all_kernel<<<5 * 4096, 256, 0, stream>>>(A16f, A4, scal);
        run_iters(A4, 0, 5);
    } else {
        for (int p = 0; p < 5; ++p) {
            a_gemm_all<<<1024, 256, 0, stream>>>(N16all, A16f, partials, p);
            mean_all_kernel<<<1, 256, 0, stream>>>(partials, scal);
            abar4_all_kernel<<<4096, 256, 0, stream>>>(A16f, A4, scal);
            run_iters(A4, p, 1);
        }
    }

    mlp_mfma_kernel<<<256, 256, 0, stream>>>(Xs16f, W1f, W2f, b1, b2, H2);
    final_kernel<<<16, 256, 0, stream>>>(H2, w3, b3, ytacc, out);
}